// Round 8
// baseline (468.257 us; speedup 1.0000x reference)
//
#include <hip/hip_runtime.h>
#include <hip/hip_bf16.h>

#define NNODES 32768
#define NEDGES 262144
#define FIN    128
#define HID1   512
#define HID2   1024
#define NGRAPH 1024
#define NCLS   20

typedef __attribute__((ext_vector_type(8))) short bf16x8;
typedef __attribute__((ext_vector_type(4))) float f32x4;

// ---- bf16 bit helpers (RNE) ----
__device__ inline float bf2f(unsigned short u) {
    union { unsigned int i; float f; } v; v.i = ((unsigned int)u) << 16; return v.f;
}
__device__ inline unsigned short f2bf(float f) {
    union { unsigned int i; float f; } v; v.f = f;
    unsigned int r = v.i + 0x7FFF + ((v.i >> 16) & 1);
    return (unsigned short)(r >> 16);
}

// ---- async global -> LDS, 16B per lane ----
typedef unsigned int u32g __attribute__((address_space(1)));
typedef unsigned int u32l __attribute__((address_space(3)));
__device__ inline void load16_lds(const void* g, void* l) {
    __builtin_amdgcn_global_load_lds((const u32g*)g, (u32l*)l, 16, 0, 0);
}

// ================= fp32 -> bf16 convert (x -> xb) =================
__global__ __launch_bounds__(256) void f2b(const float* __restrict__ X,
                                           unsigned short* __restrict__ Y, int total8) {
    int i = blockIdx.x * 256 + threadIdx.x;
    if (i >= total8) return;
    float4 a = ((const float4*)X)[i * 2];
    float4 b = ((const float4*)X)[i * 2 + 1];
    ushort4 u0, u1;
    u0.x = f2bf(a.x); u0.y = f2bf(a.y); u0.z = f2bf(a.z); u0.w = f2bf(a.w);
    u1.x = f2bf(b.x); u1.y = f2bf(b.y); u1.z = f2bf(b.z); u1.w = f2bf(b.w);
    ((ushort4*)Y)[i * 2] = u0;
    ((ushort4*)Y)[i * 2 + 1] = u1;
}

// ================= weight transpose + bf16 convert: Wt[n][k] = bf16(W[k][n]) =================
__global__ __launch_bounds__(256) void wtrans(const float* __restrict__ W,
                                              unsigned short* __restrict__ Wt,
                                              int K, int N) {
    __shared__ unsigned short tile[64][72];
    int kb = blockIdx.y * 64, nb = blockIdx.x * 64;
    {
        int k = threadIdx.x >> 2;
        int n0 = (threadIdx.x & 3) * 16;
#pragma unroll
        for (int q = 0; q < 4; ++q) {
            float4 v = *(const float4*)(W + (size_t)(kb + k) * N + nb + n0 + q * 4);
            tile[k][n0 + q * 4 + 0] = f2bf(v.x);
            tile[k][n0 + q * 4 + 1] = f2bf(v.y);
            tile[k][n0 + q * 4 + 2] = f2bf(v.z);
            tile[k][n0 + q * 4 + 3] = f2bf(v.w);
        }
    }
    __syncthreads();
    {
        int n = threadIdx.x >> 2;
        int k0 = (threadIdx.x & 3) * 16;
#pragma unroll
        for (int q = 0; q < 4; ++q) {
            ushort4 u;
            u.x = tile[k0 + q * 4 + 0][n];
            u.y = tile[k0 + q * 4 + 1][n];
            u.z = tile[k0 + q * 4 + 2][n];
            u.w = tile[k0 + q * 4 + 3][n];
            *(ushort4*)(Wt + (size_t)(nb + n) * K + kb + k0 + q * 4) = u;
        }
    }
}

// ================= CSR build (by dst) =================
__global__ __launch_bounds__(256) void csr_count(const int* __restrict__ dst, int* __restrict__ cnt) {
    int e = blockIdx.x * 256 + threadIdx.x;
    if (e < NEDGES) atomicAdd(&cnt[dst[e]], 1);
}

__global__ __launch_bounds__(1024) void csr_scan(const int* __restrict__ cnt,
                                                 int* __restrict__ offs,
                                                 int* __restrict__ cursor,
                                                 float* __restrict__ dis) {
    __shared__ int part[1024];
    int t = threadIdx.x;
    int base = t * 32;
    int s = 0;
#pragma unroll
    for (int i = 0; i < 32; ++i) s += cnt[base + i];
    part[t] = s;
    __syncthreads();
    for (int off = 1; off < 1024; off <<= 1) {
        int v = (t >= off) ? part[t - off] : 0;
        __syncthreads();
        part[t] += v;
        __syncthreads();
    }
    int run = (t == 0) ? 0 : part[t - 1];
#pragma unroll
    for (int i = 0; i < 32; ++i) {
        int c = cnt[base + i];
        offs[base + i] = run;
        cursor[base + i] = run;
        dis[base + i] = rsqrtf((float)(c + 1));
        run += c;
    }
    if (t == 1023) offs[NNODES] = run;
}

__global__ __launch_bounds__(256) void csr_fill(const int* __restrict__ src,
                                                const int* __restrict__ dst,
                                                const float* __restrict__ dis,
                                                int* __restrict__ cursor,
                                                int* __restrict__ csr_src,
                                                float* __restrict__ csr_w) {
    int e = blockIdx.x * 256 + threadIdx.x;
    if (e >= NEDGES) return;
    int s = src[e], d = dst[e];
    int pos = atomicAdd(&cursor[d], 1);
    csr_src[pos] = s;
    csr_w[pos] = dis[s] * dis[d];
}

// ================= channel-chunked gather (bf16 in, bf16 out) =================
// blockIdx.x = chunk (64 channels) -> fixed XCD subset caches its 4MB chunk of X.
// BN=1: apply per-channel scale/shift + relu to every gathered element.
template<int F, int BN>
__global__ __launch_bounds__(256) void gcn_gather_ch(const unsigned short* __restrict__ X,
                                                     const int* __restrict__ offs,
                                                     const int* __restrict__ csr_src,
                                                     const float* __restrict__ csr_w,
                                                     const float* __restrict__ dis,
                                                     const float* __restrict__ scale,
                                                     const float* __restrict__ shift,
                                                     unsigned short* __restrict__ out) {
    int lane = threadIdx.x & 63, wave = threadIdx.x >> 6;
    int chunk = blockIdx.x;
    int node = blockIdx.y * 4 + wave;
    int c = chunk * 64 + lane;
    const unsigned short* Xc = X + c;
    float sc = 0.f, sh = 0.f;
    if (BN) { sc = scale[c]; sh = shift[c]; }
    float sw = dis[node]; sw *= sw;

    float self = bf2f(Xc[(size_t)node * F]);
    if (BN) self = fmaxf(self * sc + sh, 0.f);
    float acc = sw * self;

    int e0 = offs[node], e1 = offs[node + 1];
    for (int e = e0; e < e1; ++e) {
        int s = csr_src[e];
        float w = csr_w[e];
        float v = bf2f(Xc[(size_t)s * F]);
        if (BN) v = fmaxf(v * sc + sh, 0.f);
        acc += w * v;
    }
    out[(size_t)node * F + c] = f2bf(acc);
}

// ================= bf16 MFMA GEMM: C[M][N] = A[M][K] @ B (Bt[N][K]) =================
// 128x128 tile, BK=64, 4 waves. global_load_lds staging; LDS XOR-swizzle via pre-swizzled source.
// CBF16=1: LDS-staged coalesced bf16 store. STATS=1: fused per-column sum/sumsq atomics.
// POOL=1: per-graph (32 rows) per-column raw max/min -> gmax/gmin (block owns unique slots).
template<int EPI, int CBF16, int STATS, int POOL>
__global__ __launch_bounds__(256, 2) void gemm_mfma(const unsigned short* __restrict__ A,
                                                    const unsigned short* __restrict__ Bt,
                                                    const float* __restrict__ bias,
                                                    void* __restrict__ Cv,
                                                    float* __restrict__ gsum,
                                                    float* __restrict__ gsq,
                                                    float* __restrict__ gmax,
                                                    float* __restrict__ gmin,
                                                    int M, int N, int K) {
    constexpr int BM = 128, BN = 128, BK = 64;
    __shared__ unsigned short smem[128 * 136];
    unsigned short* As = smem;
    unsigned short* Bs = smem + BM * BK;

    const int tid = threadIdx.x;
    const int lane = tid & 63;
    const int wave = tid >> 6;
    const int wr = wave >> 1, wc = wave & 1;

    const int nwg = gridDim.x * gridDim.y;
    const int wg = blockIdx.y * gridDim.x + blockIdx.x;
    const int cpx = nwg >> 3;
    const int swz = (wg & 7) * cpx + (wg >> 3);
    const int m0 = (swz / gridDim.x) * BM, n0 = (swz % gridDim.x) * BN;

    const int sub = ((tid & 7) * 16) ^ (((tid >> 3) & 7) << 4);
    const int rbase = tid >> 3;
    const char* Ab = (const char*)A + sub;
    const char* Bb = (const char*)Bt + sub;

    f32x4 acc[4][4] = {};

    for (int k0 = 0; k0 < K; k0 += BK) {
        __syncthreads();
#pragma unroll
        for (int i = 0; i < 4; ++i) {
            int r = i * 32 + rbase;
            load16_lds(Ab + ((size_t)(m0 + r) * K + k0) * 2, (char*)As + i * 4096 + tid * 16);
            load16_lds(Bb + ((size_t)(n0 + r) * K + k0) * 2, (char*)Bs + i * 4096 + tid * 16);
        }
        __syncthreads();
#pragma unroll
        for (int ks = 0; ks < 2; ++ks) {
            bf16x8 af[4], bfr[4];
#pragma unroll
            for (int m = 0; m < 4; ++m) {
                int row = wr * 64 + m * 16 + (lane & 15);
                int s = (ks * 64 + ((lane >> 4) * 16)) ^ ((row & 7) << 4);
                af[m] = *(const bf16x8*)((const char*)As + row * 128 + s);
            }
#pragma unroll
            for (int n = 0; n < 4; ++n) {
                int row = wc * 64 + n * 16 + (lane & 15);
                int s = (ks * 64 + ((lane >> 4) * 16)) ^ ((row & 7) << 4);
                bfr[n] = *(const bf16x8*)((const char*)Bs + row * 128 + s);
            }
#pragma unroll
            for (int m = 0; m < 4; ++m)
#pragma unroll
                for (int n = 0; n < 4; ++n)
                    acc[m][n] = __builtin_amdgcn_mfma_f32_16x16x32_bf16(af[m], bfr[n], acc[m][n], 0, 0, 0);
        }
    }

    // ---- epilogue ----
    if (CBF16) {
        __syncthreads();
        float cs[4], cq[4];
        float pmx[2][4], pmn[2][4];
#pragma unroll
        for (int n = 0; n < 4; ++n) {
            cs[n] = 0.f; cq[n] = 0.f;
            if (POOL) {
                pmx[0][n] = -1e30f; pmx[1][n] = -1e30f;
                pmn[0][n] = 1e30f;  pmn[1][n] = 1e30f;
            }
        }
#pragma unroll
        for (int n = 0; n < 4; ++n) {
            int col = wc * 64 + n * 16 + (lane & 15);
            float bsv = bias[n0 + col];
#pragma unroll
            for (int m = 0; m < 4; ++m) {
                int rbase2 = wr * 64 + m * 16 + ((lane >> 4) << 2);
#pragma unroll
                for (int j = 0; j < 4; ++j) {
                    float v = acc[m][n][j] + bsv;
                    if (STATS) { cs[n] += v; cq[n] += v * v; }
                    if (POOL) {
                        pmx[m >> 1][n] = fmaxf(pmx[m >> 1][n], v);
                        pmn[m >> 1][n] = fminf(pmn[m >> 1][n], v);
                    }
                    if (EPI == 1) v = fmaxf(v, 0.f);
                    smem[(rbase2 + j) * 136 + col] = f2bf(v);
                }
            }
        }
        if (STATS) {
#pragma unroll
            for (int n = 0; n < 4; ++n) {
                cs[n] += __shfl_xor(cs[n], 16); cs[n] += __shfl_xor(cs[n], 32);
                cq[n] += __shfl_xor(cq[n], 16); cq[n] += __shfl_xor(cq[n], 32);
            }
            if (lane < 16) {
#pragma unroll
                for (int n = 0; n < 4; ++n) {
                    int col = n0 + wc * 64 + n * 16 + lane;
                    atomicAdd(&gsum[col], cs[n]);
                    atomicAdd(&gsq[col],  cq[n]);
                }
            }
        }
        if (POOL) {
#pragma unroll
            for (int gi = 0; gi < 2; ++gi)
#pragma unroll
                for (int n = 0; n < 4; ++n) {
                    pmx[gi][n] = fmaxf(pmx[gi][n], __shfl_xor(pmx[gi][n], 16));
                    pmx[gi][n] = fmaxf(pmx[gi][n], __shfl_xor(pmx[gi][n], 32));
                    pmn[gi][n] = fminf(pmn[gi][n], __shfl_xor(pmn[gi][n], 16));
                    pmn[gi][n] = fminf(pmn[gi][n], __shfl_xor(pmn[gi][n], 32));
                }
            if (lane < 16) {
                int gb = (m0 >> 5) + wr * 2;
#pragma unroll
                for (int gi = 0; gi < 2; ++gi)
#pragma unroll
                    for (int n = 0; n < 4; ++n) {
                        int col = n0 + wc * 64 + n * 16 + lane;
                        gmax[(size_t)(gb + gi) * HID2 + col] = pmx[gi][n];
                        gmin[(size_t)(gb + gi) * HID2 + col] = pmn[gi][n];
                    }
            }
        }
        __syncthreads();
#pragma unroll
        for (int it = 0; it < 8; ++it) {
            int r = it * 16 + (tid >> 4);
            int ch = tid & 15;
            int4 v = *(const int4*)&smem[r * 136 + ch * 8];
            *(int4*)((unsigned short*)Cv + (size_t)(m0 + r) * N + n0 + ch * 8) = v;
        }
    } else {
#pragma unroll
        for (int m = 0; m < 4; ++m) {
            int row = m0 + wr * 64 + m * 16 + ((lane >> 4) << 2);
#pragma unroll
            for (int n = 0; n < 4; ++n) {
                int col = n0 + wc * 64 + n * 16 + (lane & 15);
                float bsv = bias[col];
#pragma unroll
                for (int j = 0; j < 4; ++j) {
                    float v = acc[m][n][j] + bsv;
                    if (EPI == 1) v = fmaxf(v, 0.f);
                    ((float*)Cv)[(size_t)(row + j) * N + col] = v;
                }
            }
        }
    }
}

__global__ void bn_finalize(const float* __restrict__ sum, const float* __restrict__ sq,
                            const float* __restrict__ w, const float* __restrict__ b,
                            float* __restrict__ scale, float* __restrict__ shift,
                            int cols, float invN) {
    int c = blockIdx.x * blockDim.x + threadIdx.x;
    if (c >= cols) return;
    float mu = sum[c] * invN;
    float var = sq[c] * invN - mu * mu;
    float sc = rsqrtf(var + 1e-5f) * w[c];
    scale[c] = sc;
    shift[c] = b[c] - mu * sc;
}

// ---------------- streaming LN1 stats of relu(bn(h2)): fixed channel ownership ----------------
__global__ __launch_bounds__(256) void lnstats_h2(const unsigned short* __restrict__ H,
                                                  const float* __restrict__ scale,
                                                  const float* __restrict__ shift,
                                                  double* __restrict__ lnacc) {
    int half = threadIdx.x >> 7;              // 0..1
    int c0 = (threadIdx.x & 127) * 8;
    float sc[8], sh[8];
    *(float4*)&sc[0] = *(const float4*)(scale + c0);
    *(float4*)&sc[4] = *(const float4*)(scale + c0 + 4);
    *(float4*)&sh[0] = *(const float4*)(shift + c0);
    *(float4*)&sh[4] = *(const float4*)(shift + c0 + 4);
    float lsum = 0.f, lsq = 0.f;
    for (int r = blockIdx.x * 2 + half; r < NNODES; r += gridDim.x * 2) {
        int4 u = *(const int4*)(H + (size_t)r * HID2 + c0);
        const unsigned short* up = (const unsigned short*)&u;
#pragma unroll
        for (int q = 0; q < 8; ++q) {
            float v = fmaxf(bf2f(up[q]) * sc[q] + sh[q], 0.f);
            lsum += v; lsq += v * v;
        }
    }
    for (int o = 32; o > 0; o >>= 1) {
        lsum += __shfl_down(lsum, o);
        lsq  += __shfl_down(lsq, o);
    }
    __shared__ float w1[4], w2[4];
    int wid = threadIdx.x >> 6, lane = threadIdx.x & 63;
    if (lane == 0) { w1[wid] = lsum; w2[wid] = lsq; }
    __syncthreads();
    if (threadIdx.x == 0) {
        atomicAdd(lnacc,     (double)(w1[0] + w1[1] + w1[2] + w1[3]));
        atomicAdd(lnacc + 1, (double)(w2[0] + w2[1] + w2[2] + w2[3]));
    }
}

// ---------------- pool finalize: compose bn+relu+ln over raw max/min (sign-correct) ----------------
__global__ __launch_bounds__(256) void pool_fin(const float* __restrict__ gmax,
                                                const float* __restrict__ gmin,
                                                const float* __restrict__ sc_,
                                                const float* __restrict__ sh_,
                                                const float* __restrict__ a,
                                                const float* __restrict__ c,
                                                unsigned short* __restrict__ P) {
    int i = blockIdx.x * 256 + threadIdx.x;            // over NGRAPH*HID2/4
    int c0 = (i * 4) & (HID2 - 1);
    float4 scv = *(const float4*)(sc_ + c0);
    float4 shv = *(const float4*)(sh_ + c0);
    float4 av = *(const float4*)(a + c0);
    float4 cv = *(const float4*)(c + c0);
    float4 mx = ((const float4*)gmax)[i];
    float4 mn = ((const float4*)gmin)[i];
    float4 r;
    {
        float vs = ((scv.x >= 0.f) == (av.x >= 0.f)) ? mx.x : mn.x;
        r.x = av.x * fmaxf(scv.x * vs + shv.x, 0.f) + cv.x;
        vs = ((scv.y >= 0.f) == (av.y >= 0.f)) ? mx.y : mn.y;
        r.y = av.y * fmaxf(scv.y * vs + shv.y, 0.f) + cv.y;
        vs = ((scv.z >= 0.f) == (av.z >= 0.f)) ? mx.z : mn.z;
        r.z = av.z * fmaxf(scv.z * vs + shv.z, 0.f) + cv.z;
        vs = ((scv.w >= 0.f) == (av.w >= 0.f)) ? mx.w : mn.w;
        r.w = av.w * fmaxf(scv.w * vs + shv.w, 0.f) + cv.w;
    }
    ushort4 o;
    o.x = f2bf(r.x); o.y = f2bf(r.y); o.z = f2bf(r.z); o.w = f2bf(r.w);
    ((ushort4*)P)[i] = o;
}

// ---------------- global stats (LN2 over z, fp32) ----------------
__global__ __launch_bounds__(256) void global_stats(const float* __restrict__ X, int total4, double* acc) {
    float s = 0.f, ss = 0.f;
    for (int t = blockIdx.x * 256 + threadIdx.x; t < total4; t += gridDim.x * 256) {
        float4 v = ((const float4*)X)[t];
        s  += v.x + v.y + v.z + v.w;
        ss += v.x * v.x + v.y * v.y + v.z * v.z + v.w * v.w;
    }
    for (int o = 32; o > 0; o >>= 1) {
        s += __shfl_down(s, o);
        ss += __shfl_down(ss, o);
    }
    __shared__ float w1[4], w2[4];
    int wid = threadIdx.x >> 6, lane = threadIdx.x & 63;
    if (lane == 0) { w1[wid] = s; w2[wid] = ss; }
    __syncthreads();
    if (threadIdx.x == 0) {
        atomicAdd(acc,     (double)(w1[0] + w1[1] + w1[2] + w1[3]));
        atomicAdd(acc + 1, (double)(w2[0] + w2[1] + w2[2] + w2[3]));
    }
}

// ---------------- LN finalize: per-channel affine a[c], c[c] ----------------
__global__ void ln_finalize(const double* __restrict__ acc, const float* __restrict__ w,
                            const float* __restrict__ b, float* __restrict__ a,
                            float* __restrict__ c, int cols, double invCount) {
    __shared__ float smu, sinv;
    if (threadIdx.x == 0) {
        double mu  = acc[0] * invCount;
        double var = acc[1] * invCount - mu * mu;
        if (var < 0.0) var = 0.0;
        float stdv = sqrtf((float)var);
        smu = (float)mu;
        sinv = 1.0f / (stdv + 1e-5f);
    }
    __syncthreads();
    int ci = threadIdx.x;
    if (ci < cols) {
        float A = sinv * w[ci];
        a[ci] = A;
        c[ci] = b[ci] - smu * A;
    }
}

// ---------------- fused LN2 + final GEMM [1024,512]@[512,20] + log_softmax ----------------
__global__ __launch_bounds__(64) void gemm4_lsm(const float* __restrict__ Z,
                                                const float* __restrict__ a,
                                                const float* __restrict__ c,
                                                const float* __restrict__ W,
                                                const float* __restrict__ bias,
                                                float* __restrict__ out) {
    __shared__ float zs[HID1];
    __shared__ float logits[NCLS];
    __shared__ float smax, slse;
    int m = blockIdx.x;
    for (int k = threadIdx.x; k < HID1; k += 64)
        zs[k] = Z[(size_t)m * HID1 + k] * a[k] + c[k];
    __syncthreads();
    if (threadIdx.x < NCLS) {
        float acc = bias[threadIdx.x];
        for (int k = 0; k < HID1; ++k)
            acc += zs[k] * W[k * NCLS + threadIdx.x];
        logits[threadIdx.x] = acc;
    }
    __syncthreads();
    if (threadIdx.x == 0) {
        float mx = -1e30f;
        for (int j = 0; j < NCLS; ++j) mx = fmaxf(mx, logits[j]);
        float s = 0.f;
        for (int j = 0; j < NCLS; ++j) s += expf(logits[j] - mx);
        smax = mx; slse = logf(s);
    }
    __syncthreads();
    if (threadIdx.x < NCLS)
        out[(size_t)m * NCLS + threadIdx.x] = logits[threadIdx.x] - smax - slse;
}

// ======================== launch ========================
extern "C" void kernel_launch(void* const* d_in, const int* in_sizes, int n_in,
                              void* d_out, int out_size, void* d_ws, size_t ws_size,
                              hipStream_t stream) {
    const float* x       = (const float*)d_in[0];
    const int*   ei      = (const int*)d_in[1];
    const int*   src     = ei;
    const int*   dst     = ei + NEDGES;
    const float* conv1_w = (const float*)d_in[3];
    const float* conv1_b = (const float*)d_in[4];
    const float* bn1_w   = (const float*)d_in[5];
    const float* bn1_b   = (const float*)d_in[6];
    const float* conv2_w = (const float*)d_in[7];
    const float* conv2_b = (const float*)d_in[8];
    const float* bn2_w   = (const float*)d_in[9];
    const float* bn2_b   = (const float*)d_in[10];
    const float* ln1_w   = (const float*)d_in[11];
    const float* ln1_b   = (const float*)d_in[12];
    const float* lin1_w  = (const float*)d_in[13];
    const float* lin1_b  = (const float*)d_in[14];
    const float* ln2_w   = (const float*)d_in[15];
    const float* ln2_b   = (const float*)d_in[16];
    const float* lin2_w  = (const float*)d_in[17];
    const float* lin2_b  = (const float*)d_in[18];
    float* out = (float*)d_out;

    // ---- workspace layout (peak 128 MB) ----
    char* ws = (char*)d_ws;
    const size_t KB = 1024, MB = 1048576;
    float*          dis     = (float*)(ws + 0);            // 128K
    float*          sF      = (float*)(ws + 128 * KB);     // 64K stats
    unsigned short* w1t     = (unsigned short*)(ws + 256 * KB);   // [512][128]  128K
    unsigned short* w2t     = (unsigned short*)(ws + 512 * KB);   // [1024][512] 1M
    unsigned short* w3t     = (unsigned short*)(ws + 1536 * KB);  // [512][1024] 1M
    int*            cnt     = (int*)(ws + 2560 * KB);      // 128K
    int*            offs    = (int*)(ws + 2688 * KB);      // 128K+4 (192K reserved)
    int*            cursor  = (int*)(ws + 2880 * KB);      // 128K
    int*            csr_src = (int*)(ws + 3 * MB);         // 1M
    float*          csr_w   = (float*)(ws + 4 * MB);       // 1M
    unsigned short* pool    = (unsigned short*)(ws + 5 * MB);   // [1024][1024] bf16 2M
    float*          z       = (float*)(ws + 7 * MB);       // [1024][512] f32 2M
    unsigned short* agg1    = (unsigned short*)(ws + 16 * MB);  // [N,128] bf16 8M   (16-24)
    unsigned short* h1      = (unsigned short*)(ws + 24 * MB);  // [N,512] bf16 32M  (24-56)
    unsigned short* h2      = (unsigned short*)(ws + 16 * MB);  // [N,1024] bf16 64M (16-80, overlays dead agg1+h1)
    float*          gmax    = (float*)(ws + 80 * MB);      // [G,1024] f32 4M (80-84)
    float*          gmin    = (float*)(ws + 84 * MB);      // [G,1024] f32 4M (84-88)
    unsigned short* agg2    = (unsigned short*)(ws + 88 * MB);  // [N,512] bf16 32M  (88-120)
    unsigned short* xb      = (unsigned short*)(ws + 120 * MB); // [N,128] bf16 8M  (120-128)

    float* bn1_sum = sF + 0,      *bn1_sq    = sF + 512;
    float* bn1_scale = sF + 1024, *bn1_shift = sF + 1536;
    float* bn2_sum = sF + 2048,   *bn2_sq    = sF + 3072;
    float* bn2_scale = sF + 4096, *bn2_shift = sF + 5120;
    float* ln1_a = sF + 6144, *ln1_c = sF + 7168;
    float* ln2_a = sF + 8192, *ln2_c = sF + 8704;
    double* lnacc = (double*)(sF + 9216);   // [0,1]=ln1  [2,3]=ln2

    hipMemsetAsync(sF, 0, 40960, stream);
    hipMemsetAsync(cnt, 0, NNODES * 4, stream);

    // ---- x -> bf16 ----
    f2b<<<NNODES * FIN / 8 / 256, 256, 0, stream>>>(x, xb, NNODES * FIN / 8);

    // ---- weight transposes (bf16) ----
    wtrans<<<dim3(HID1 / 64, FIN / 64),  256, 0, stream>>>(conv1_w, w1t, FIN, HID1);
    wtrans<<<dim3(HID2 / 64, HID1 / 64), 256, 0, stream>>>(conv2_w, w2t, HID1, HID2);
    wtrans<<<dim3(HID1 / 64, HID2 / 64), 256, 0, stream>>>(lin1_w,  w3t, HID2, HID1);

    // ---- CSR build (by dst) + dis ----
    csr_count<<<(NEDGES + 255) / 256, 256, 0, stream>>>(dst, cnt);
    csr_scan<<<1, 1024, 0, stream>>>(cnt, offs, cursor, dis);
    csr_fill<<<(NEDGES + 255) / 256, 256, 0, stream>>>(src, dst, dis, cursor, csr_src, csr_w);

    // ---- conv1: agg1 = A @ xb (chunked) ; h1 = agg1 @ W1 + b1 (+ bn1 col stats) ----
    gcn_gather_ch<FIN, 0><<<dim3(FIN / 64, NNODES / 4), 256, 0, stream>>>(xb, offs, csr_src, csr_w, dis, nullptr, nullptr, agg1);
    gemm_mfma<0, 1, 1, 0><<<dim3(HID1 / 128, NNODES / 128), 256, 0, stream>>>(agg1, w1t, conv1_b, h1, bn1_sum, bn1_sq, nullptr, nullptr, NNODES, HID1, FIN);

    // ---- bn1 coeffs; conv2 gather applies BN1+ReLU on the fly (chunked, XCD-affine) ----
    bn_finalize<<<(HID1 + 255) / 256, 256, 0, stream>>>(bn1_sum, bn1_sq, bn1_w, bn1_b, bn1_scale, bn1_shift, HID1, 1.0f / NNODES);
    gcn_gather_ch<HID1, 1><<<dim3(HID1 / 64, NNODES / 4), 256, 0, stream>>>(h1, offs, csr_src, csr_w, dis, bn1_scale, bn1_shift, agg2);
    gemm_mfma<0, 1, 1, 1><<<dim3(HID2 / 128, NNODES / 128), 256, 0, stream>>>(agg2, w2t, conv2_b, h2, bn2_sum, bn2_sq, gmax, gmin, NNODES, HID2, HID1);

    // ---- bn2 coeffs; streaming LN1 stats over relu(bn(h2)) ----
    bn_finalize<<<(HID2 + 255) / 256, 256, 0, stream>>>(bn2_sum, bn2_sq, bn2_w, bn2_b, bn2_scale, bn2_shift, HID2, 1.0f / NNODES);
    lnstats_h2<<<1024, 256, 0, stream>>>(h2, bn2_scale, bn2_shift, lnacc);

    // ---- LN1 affine + pool finalize (bn+relu+ln composed over raw max/min) ----
    ln_finalize<<<1, HID2, 0, stream>>>(lnacc, ln1_w, ln1_b, ln1_a, ln1_c, HID2, 1.0 / ((double)NNODES * HID2));
    pool_fin<<<NGRAPH * HID2 / 4 / 256, 256, 0, stream>>>(gmax, gmin, bn2_scale, bn2_shift, ln1_a, ln1_c, pool);

    // ---- lin1 + relu (MFMA, f32 out) ----
    gemm_mfma<1, 0, 0, 0><<<dim3(HID1 / 128, NGRAPH / 128), 256, 0, stream>>>(pool, w3t, lin1_b, z, nullptr, nullptr, nullptr, nullptr, NGRAPH, HID1, HID2);

    // ---- LN2 + lin2 + log_softmax ----
    global_stats<<<512, 256, 0, stream>>>(z, NGRAPH * HID1 / 4, lnacc + 2);
    ln_finalize<<<1, HID1, 0, stream>>>(lnacc + 2, ln2_w, ln2_b, ln2_a, ln2_c, HID1, 1.0 / ((double)NGRAPH * HID1));
    gemm4_lsm<<<NGRAPH, 64, 0, stream>>>(z, ln2_a, ln2_c, lin2_w, lin2_b, out);
}

// Round 9
// 303.811 us; speedup vs baseline: 1.5413x; 1.5413x over previous
//
#include <hip/hip_runtime.h>
#include <hip/hip_bf16.h>

#define NNODES 32768
#define NEDGES 262144
#define FIN    128
#define HID1   512
#define HID2   1024
#define NGRAPH 1024
#define NCLS   20

typedef __attribute__((ext_vector_type(8))) short bf16x8;
typedef __attribute__((ext_vector_type(4))) float f32x4;

// ---- bf16 bit helpers (RNE) ----
__device__ inline float bf2f(unsigned short u) {
    union { unsigned int i; float f; } v; v.i = ((unsigned int)u) << 16; return v.f;
}
__device__ inline unsigned short f2bf(float f) {
    union { unsigned int i; float f; } v; v.f = f;
    unsigned int r = v.i + 0x7FFF + ((v.i >> 16) & 1);
    return (unsigned short)(r >> 16);
}

// ---- async global -> LDS, 16B per lane ----
typedef unsigned int u32g __attribute__((address_space(1)));
typedef unsigned int u32l __attribute__((address_space(3)));
__device__ inline void load16_lds(const void* g, void* l) {
    __builtin_amdgcn_global_load_lds((const u32g*)g, (u32l*)l, 16, 0, 0);
}

// ================= fp32 -> bf16 convert (x -> xb) =================
__global__ __launch_bounds__(256) void f2b(const float* __restrict__ X,
                                           unsigned short* __restrict__ Y, int total8) {
    int i = blockIdx.x * 256 + threadIdx.x;
    if (i >= total8) return;
    float4 a = ((const float4*)X)[i * 2];
    float4 b = ((const float4*)X)[i * 2 + 1];
    ushort4 u0, u1;
    u0.x = f2bf(a.x); u0.y = f2bf(a.y); u0.z = f2bf(a.z); u0.w = f2bf(a.w);
    u1.x = f2bf(b.x); u1.y = f2bf(b.y); u1.z = f2bf(b.z); u1.w = f2bf(b.w);
    ((ushort4*)Y)[i * 2] = u0;
    ((ushort4*)Y)[i * 2 + 1] = u1;
}

// ================= weight transpose + bf16 convert: Wt[n][k] = bf16(W[k][n]) =================
__global__ __launch_bounds__(256) void wtrans(const float* __restrict__ W,
                                              unsigned short* __restrict__ Wt,
                                              int K, int N) {
    __shared__ unsigned short tile[64][72];
    int kb = blockIdx.y * 64, nb = blockIdx.x * 64;
    {
        int k = threadIdx.x >> 2;
        int n0 = (threadIdx.x & 3) * 16;
#pragma unroll
        for (int q = 0; q < 4; ++q) {
            float4 v = *(const float4*)(W + (size_t)(kb + k) * N + nb + n0 + q * 4);
            tile[k][n0 + q * 4 + 0] = f2bf(v.x);
            tile[k][n0 + q * 4 + 1] = f2bf(v.y);
            tile[k][n0 + q * 4 + 2] = f2bf(v.z);
            tile[k][n0 + q * 4 + 3] = f2bf(v.w);
        }
    }
    __syncthreads();
    {
        int n = threadIdx.x >> 2;
        int k0 = (threadIdx.x & 3) * 16;
#pragma unroll
        for (int q = 0; q < 4; ++q) {
            ushort4 u;
            u.x = tile[k0 + q * 4 + 0][n];
            u.y = tile[k0 + q * 4 + 1][n];
            u.z = tile[k0 + q * 4 + 2][n];
            u.w = tile[k0 + q * 4 + 3][n];
            *(ushort4*)(Wt + (size_t)(nb + n) * K + kb + k0 + q * 4) = u;
        }
    }
}

// ================= CSR build (by dst) =================
__global__ __launch_bounds__(256) void csr_count(const int* __restrict__ dst, int* __restrict__ cnt) {
    int e = blockIdx.x * 256 + threadIdx.x;
    if (e < NEDGES) atomicAdd(&cnt[dst[e]], 1);
}

__global__ __launch_bounds__(1024) void csr_scan(const int* __restrict__ cnt,
                                                 int* __restrict__ offs,
                                                 int* __restrict__ cursor,
                                                 float* __restrict__ dis) {
    __shared__ int part[1024];
    int t = threadIdx.x;
    int base = t * 32;
    int s = 0;
#pragma unroll
    for (int i = 0; i < 32; ++i) s += cnt[base + i];
    part[t] = s;
    __syncthreads();
    for (int off = 1; off < 1024; off <<= 1) {
        int v = (t >= off) ? part[t - off] : 0;
        __syncthreads();
        part[t] += v;
        __syncthreads();
    }
    int run = (t == 0) ? 0 : part[t - 1];
#pragma unroll
    for (int i = 0; i < 32; ++i) {
        int c = cnt[base + i];
        offs[base + i] = run;
        cursor[base + i] = run;
        dis[base + i] = rsqrtf((float)(c + 1));
        run += c;
    }
    if (t == 1023) offs[NNODES] = run;
}

__global__ __launch_bounds__(256) void csr_fill(const int* __restrict__ src,
                                                const int* __restrict__ dst,
                                                const float* __restrict__ dis,
                                                int* __restrict__ cursor,
                                                int* __restrict__ csr_src,
                                                float* __restrict__ csr_w) {
    int e = blockIdx.x * 256 + threadIdx.x;
    if (e >= NEDGES) return;
    int s = src[e], d = dst[e];
    int pos = atomicAdd(&cursor[d], 1);
    csr_src[pos] = s;
    csr_w[pos] = dis[s] * dis[d];
}

// ================= gather aggregation (bf16 in, bf16 out), one wave per node =================
// CPL = F/64 channels per lane; 16B int4 row loads (CPL==8) / 4B (CPL==2); 2-edge unroll.
// BN=1: apply per-channel scale/shift + relu to every gathered row.
template<int F, int BN>
__global__ __launch_bounds__(256) void gcn_gather(const unsigned short* __restrict__ X,
                                                  const int* __restrict__ offs,
                                                  const int* __restrict__ csr_src,
                                                  const float* __restrict__ csr_w,
                                                  const float* __restrict__ dis,
                                                  const float* __restrict__ scale,
                                                  const float* __restrict__ shift,
                                                  unsigned short* __restrict__ out) {
    constexpr int CPL = F / 64;          // 2 (F=128) or 8 (F=512)
    int wave = threadIdx.x >> 6, lane = threadIdx.x & 63;
    int node = blockIdx.x * 4 + wave;
    int c0 = lane * CPL;
    const unsigned short* Xc = X + c0;
    float acc[CPL];
#pragma unroll
    for (int q = 0; q < CPL; ++q) acc[q] = 0.f;
    float sc[CPL], sh[CPL];
    if (BN) {
#pragma unroll
        for (int q = 0; q < CPL; ++q) { sc[q] = scale[c0 + q]; sh[q] = shift[c0 + q]; }
    }

    // row accumulate helper (unpack from 16B/4B load)
    auto accum = [&](int s, float w) {
        if (CPL == 8) {
            int4 u = *(const int4*)(Xc + (size_t)s * F);
            const unsigned short* up = (const unsigned short*)&u;
#pragma unroll
            for (int q = 0; q < 8; ++q) {
                float v = bf2f(up[q]);
                if (BN) v = fmaxf(v * sc[q] + sh[q], 0.f);
                acc[q] += w * v;
            }
        } else {
            ushort2 u = *(const ushort2*)(Xc + (size_t)s * F);
            float v0 = bf2f(u.x), v1 = bf2f(u.y);
            if (BN) {
                v0 = fmaxf(v0 * sc[0] + sh[0], 0.f);
                v1 = fmaxf(v1 * sc[1] + sh[1], 0.f);
            }
            acc[0] += w * v0; acc[1] += w * v1;
        }
    };

    float sw = dis[node]; sw *= sw;
    accum(node, sw);                       // self-loop term

    int e0 = offs[node], e1 = offs[node + 1];
    int e = e0;
    for (; e + 2 <= e1; e += 2) {          // 2-edge unroll: 2 independent row loads in flight
        int s0 = csr_src[e], s1 = csr_src[e + 1];
        float w0 = csr_w[e], w1 = csr_w[e + 1];
        accum(s0, w0);
        accum(s1, w1);
    }
    if (e < e1) accum(csr_src[e], csr_w[e]);

    unsigned short* o = out + (size_t)node * F + c0;
    if (CPL == 2) {
        ushort2 u; u.x = f2bf(acc[0]); u.y = f2bf(acc[1]);
        *(ushort2*)o = u;
    } else {
        ushort4 u0, u1;
        u0.x = f2bf(acc[0]); u0.y = f2bf(acc[1]); u0.z = f2bf(acc[2]); u0.w = f2bf(acc[3]);
        u1.x = f2bf(acc[4]); u1.y = f2bf(acc[5]); u1.z = f2bf(acc[6]); u1.w = f2bf(acc[7]);
        *(ushort4*)o = u0;
        *(ushort4*)(o + 4) = u1;
    }
}

// ================= bf16 MFMA GEMM: C[M][N] = A[M][K] @ B (Bt[N][K]) =================
// 128x128 tile, BK=64, 4 waves. global_load_lds staging; LDS XOR-swizzle via pre-swizzled source.
// CBF16=1: LDS-staged coalesced bf16 store. STATS=1: fused per-column sum/sumsq atomics.
// POOL=1: per-graph (32 rows) per-column raw max/min -> gmax/gmin (block owns unique slots).
template<int EPI, int CBF16, int STATS, int POOL>
__global__ __launch_bounds__(256, 2) void gemm_mfma(const unsigned short* __restrict__ A,
                                                    const unsigned short* __restrict__ Bt,
                                                    const float* __restrict__ bias,
                                                    void* __restrict__ Cv,
                                                    float* __restrict__ gsum,
                                                    float* __restrict__ gsq,
                                                    float* __restrict__ gmax,
                                                    float* __restrict__ gmin,
                                                    int M, int N, int K) {
    constexpr int BM = 128, BN = 128, BK = 64;
    __shared__ unsigned short smem[128 * 136];
    unsigned short* As = smem;
    unsigned short* Bs = smem + BM * BK;

    const int tid = threadIdx.x;
    const int lane = tid & 63;
    const int wave = tid >> 6;
    const int wr = wave >> 1, wc = wave & 1;

    const int nwg = gridDim.x * gridDim.y;
    const int wg = blockIdx.y * gridDim.x + blockIdx.x;
    const int cpx = nwg >> 3;
    const int swz = (wg & 7) * cpx + (wg >> 3);
    const int m0 = (swz / gridDim.x) * BM, n0 = (swz % gridDim.x) * BN;

    const int sub = ((tid & 7) * 16) ^ (((tid >> 3) & 7) << 4);
    const int rbase = tid >> 3;
    const char* Ab = (const char*)A + sub;
    const char* Bb = (const char*)Bt + sub;

    f32x4 acc[4][4] = {};

    for (int k0 = 0; k0 < K; k0 += BK) {
        __syncthreads();
#pragma unroll
        for (int i = 0; i < 4; ++i) {
            int r = i * 32 + rbase;
            load16_lds(Ab + ((size_t)(m0 + r) * K + k0) * 2, (char*)As + i * 4096 + tid * 16);
            load16_lds(Bb + ((size_t)(n0 + r) * K + k0) * 2, (char*)Bs + i * 4096 + tid * 16);
        }
        __syncthreads();
#pragma unroll
        for (int ks = 0; ks < 2; ++ks) {
            bf16x8 af[4], bfr[4];
#pragma unroll
            for (int m = 0; m < 4; ++m) {
                int row = wr * 64 + m * 16 + (lane & 15);
                int s = (ks * 64 + ((lane >> 4) * 16)) ^ ((row & 7) << 4);
                af[m] = *(const bf16x8*)((const char*)As + row * 128 + s);
            }
#pragma unroll
            for (int n = 0; n < 4; ++n) {
                int row = wc * 64 + n * 16 + (lane & 15);
                int s = (ks * 64 + ((lane >> 4) * 16)) ^ ((row & 7) << 4);
                bfr[n] = *(const bf16x8*)((const char*)Bs + row * 128 + s);
            }
#pragma unroll
            for (int m = 0; m < 4; ++m)
#pragma unroll
                for (int n = 0; n < 4; ++n)
                    acc[m][n] = __builtin_amdgcn_mfma_f32_16x16x32_bf16(af[m], bfr[n], acc[m][n], 0, 0, 0);
        }
    }

    // ---- epilogue ----
    if (CBF16) {
        __syncthreads();
        float cs[4], cq[4];
        float pmx[2][4], pmn[2][4];
#pragma unroll
        for (int n = 0; n < 4; ++n) {
            cs[n] = 0.f; cq[n] = 0.f;
            if (POOL) {
                pmx[0][n] = -1e30f; pmx[1][n] = -1e30f;
                pmn[0][n] = 1e30f;  pmn[1][n] = 1e30f;
            }
        }
#pragma unroll
        for (int n = 0; n < 4; ++n) {
            int col = wc * 64 + n * 16 + (lane & 15);
            float bsv = bias[n0 + col];
#pragma unroll
            for (int m = 0; m < 4; ++m) {
                int rbase2 = wr * 64 + m * 16 + ((lane >> 4) << 2);
#pragma unroll
                for (int j = 0; j < 4; ++j) {
                    float v = acc[m][n][j] + bsv;
                    if (STATS) { cs[n] += v; cq[n] += v * v; }
                    if (POOL) {
                        pmx[m >> 1][n] = fmaxf(pmx[m >> 1][n], v);
                        pmn[m >> 1][n] = fminf(pmn[m >> 1][n], v);
                    }
                    if (EPI == 1) v = fmaxf(v, 0.f);
                    smem[(rbase2 + j) * 136 + col] = f2bf(v);
                }
            }
        }
        if (STATS) {
#pragma unroll
            for (int n = 0; n < 4; ++n) {
                cs[n] += __shfl_xor(cs[n], 16); cs[n] += __shfl_xor(cs[n], 32);
                cq[n] += __shfl_xor(cq[n], 16); cq[n] += __shfl_xor(cq[n], 32);
            }
            if (lane < 16) {
#pragma unroll
                for (int n = 0; n < 4; ++n) {
                    int col = n0 + wc * 64 + n * 16 + lane;
                    atomicAdd(&gsum[col], cs[n]);
                    atomicAdd(&gsq[col],  cq[n]);
                }
            }
        }
        if (POOL) {
#pragma unroll
            for (int gi = 0; gi < 2; ++gi)
#pragma unroll
                for (int n = 0; n < 4; ++n) {
                    pmx[gi][n] = fmaxf(pmx[gi][n], __shfl_xor(pmx[gi][n], 16));
                    pmx[gi][n] = fmaxf(pmx[gi][n], __shfl_xor(pmx[gi][n], 32));
                    pmn[gi][n] = fminf(pmn[gi][n], __shfl_xor(pmn[gi][n], 16));
                    pmn[gi][n] = fminf(pmn[gi][n], __shfl_xor(pmn[gi][n], 32));
                }
            if (lane < 16) {
                int gb = (m0 >> 5) + wr * 2;
#pragma unroll
                for (int gi = 0; gi < 2; ++gi)
#pragma unroll
                    for (int n = 0; n < 4; ++n) {
                        int col = n0 + wc * 64 + n * 16 + lane;
                        gmax[(size_t)(gb + gi) * HID2 + col] = pmx[gi][n];
                        gmin[(size_t)(gb + gi) * HID2 + col] = pmn[gi][n];
                    }
            }
        }
        __syncthreads();
#pragma unroll
        for (int it = 0; it < 8; ++it) {
            int r = it * 16 + (tid >> 4);
            int ch = tid & 15;
            int4 v = *(const int4*)&smem[r * 136 + ch * 8];
            *(int4*)((unsigned short*)Cv + (size_t)(m0 + r) * N + n0 + ch * 8) = v;
        }
    } else {
#pragma unroll
        for (int m = 0; m < 4; ++m) {
            int row = m0 + wr * 64 + m * 16 + ((lane >> 4) << 2);
#pragma unroll
            for (int n = 0; n < 4; ++n) {
                int col = n0 + wc * 64 + n * 16 + (lane & 15);
                float bsv = bias[col];
#pragma unroll
                for (int j = 0; j < 4; ++j) {
                    float v = acc[m][n][j] + bsv;
                    if (EPI == 1) v = fmaxf(v, 0.f);
                    ((float*)Cv)[(size_t)(row + j) * N + col] = v;
                }
            }
        }
    }
}

__global__ void bn_finalize(const float* __restrict__ sum, const float* __restrict__ sq,
                            const float* __restrict__ w, const float* __restrict__ b,
                            float* __restrict__ scale, float* __restrict__ shift,
                            int cols, float invN) {
    int c = blockIdx.x * blockDim.x + threadIdx.x;
    if (c >= cols) return;
    float mu = sum[c] * invN;
    float var = sq[c] * invN - mu * mu;
    float sc = rsqrtf(var + 1e-5f) * w[c];
    scale[c] = sc;
    shift[c] = b[c] - mu * sc;
}

// ---------------- streaming LN1 stats of relu(bn(h2)): fixed channel ownership ----------------
__global__ __launch_bounds__(256) void lnstats_h2(const unsigned short* __restrict__ H,
                                                  const float* __restrict__ scale,
                                                  const float* __restrict__ shift,
                                                  double* __restrict__ lnacc) {
    int half = threadIdx.x >> 7;              // 0..1
    int c0 = (threadIdx.x & 127) * 8;
    float sc[8], sh[8];
    *(float4*)&sc[0] = *(const float4*)(scale + c0);
    *(float4*)&sc[4] = *(const float4*)(scale + c0 + 4);
    *(float4*)&sh[0] = *(const float4*)(shift + c0);
    *(float4*)&sh[4] = *(const float4*)(shift + c0 + 4);
    float lsum = 0.f, lsq = 0.f;
    for (int r = blockIdx.x * 2 + half; r < NNODES; r += gridDim.x * 2) {
        int4 u = *(const int4*)(H + (size_t)r * HID2 + c0);
        const unsigned short* up = (const unsigned short*)&u;
#pragma unroll
        for (int q = 0; q < 8; ++q) {
            float v = fmaxf(bf2f(up[q]) * sc[q] + sh[q], 0.f);
            lsum += v; lsq += v * v;
        }
    }
    for (int o = 32; o > 0; o >>= 1) {
        lsum += __shfl_down(lsum, o);
        lsq  += __shfl_down(lsq, o);
    }
    __shared__ float w1[4], w2[4];
    int wid = threadIdx.x >> 6, lane = threadIdx.x & 63;
    if (lane == 0) { w1[wid] = lsum; w2[wid] = lsq; }
    __syncthreads();
    if (threadIdx.x == 0) {
        atomicAdd(lnacc,     (double)(w1[0] + w1[1] + w1[2] + w1[3]));
        atomicAdd(lnacc + 1, (double)(w2[0] + w2[1] + w2[2] + w2[3]));
    }
}

// ---------------- pool finalize: compose bn+relu+ln over raw max/min (sign-correct) ----------------
__global__ __launch_bounds__(256) void pool_fin(const float* __restrict__ gmax,
                                                const float* __restrict__ gmin,
                                                const float* __restrict__ sc_,
                                                const float* __restrict__ sh_,
                                                const float* __restrict__ a,
                                                const float* __restrict__ c,
                                                unsigned short* __restrict__ P) {
    int i = blockIdx.x * 256 + threadIdx.x;            // over NGRAPH*HID2/4
    int c0 = (i * 4) & (HID2 - 1);
    float4 scv = *(const float4*)(sc_ + c0);
    float4 shv = *(const float4*)(sh_ + c0);
    float4 av = *(const float4*)(a + c0);
    float4 cv = *(const float4*)(c + c0);
    float4 mx = ((const float4*)gmax)[i];
    float4 mn = ((const float4*)gmin)[i];
    float4 r;
    {
        float vs = ((scv.x >= 0.f) == (av.x >= 0.f)) ? mx.x : mn.x;
        r.x = av.x * fmaxf(scv.x * vs + shv.x, 0.f) + cv.x;
        vs = ((scv.y >= 0.f) == (av.y >= 0.f)) ? mx.y : mn.y;
        r.y = av.y * fmaxf(scv.y * vs + shv.y, 0.f) + cv.y;
        vs = ((scv.z >= 0.f) == (av.z >= 0.f)) ? mx.z : mn.z;
        r.z = av.z * fmaxf(scv.z * vs + shv.z, 0.f) + cv.z;
        vs = ((scv.w >= 0.f) == (av.w >= 0.f)) ? mx.w : mn.w;
        r.w = av.w * fmaxf(scv.w * vs + shv.w, 0.f) + cv.w;
    }
    ushort4 o;
    o.x = f2bf(r.x); o.y = f2bf(r.y); o.z = f2bf(r.z); o.w = f2bf(r.w);
    ((ushort4*)P)[i] = o;
}

// ---------------- global stats (LN2 over z, fp32) ----------------
__global__ __launch_bounds__(256) void global_stats(const float* __restrict__ X, int total4, double* acc) {
    float s = 0.f, ss = 0.f;
    for (int t = blockIdx.x * 256 + threadIdx.x; t < total4; t += gridDim.x * 256) {
        float4 v = ((const float4*)X)[t];
        s  += v.x + v.y + v.z + v.w;
        ss += v.x * v.x + v.y * v.y + v.z * v.z + v.w * v.w;
    }
    for (int o = 32; o > 0; o >>= 1) {
        s += __shfl_down(s, o);
        ss += __shfl_down(ss, o);
    }
    __shared__ float w1[4], w2[4];
    int wid = threadIdx.x >> 6, lane = threadIdx.x & 63;
    if (lane == 0) { w1[wid] = s; w2[wid] = ss; }
    __syncthreads();
    if (threadIdx.x == 0) {
        atomicAdd(acc,     (double)(w1[0] + w1[1] + w1[2] + w1[3]));
        atomicAdd(acc + 1, (double)(w2[0] + w2[1] + w2[2] + w2[3]));
    }
}

// ---------------- LN finalize: per-channel affine a[c], c[c] ----------------
__global__ void ln_finalize(const double* __restrict__ acc, const float* __restrict__ w,
                            const float* __restrict__ b, float* __restrict__ a,
                            float* __restrict__ c, int cols, double invCount) {
    __shared__ float smu, sinv;
    if (threadIdx.x == 0) {
        double mu  = acc[0] * invCount;
        double var = acc[1] * invCount - mu * mu;
        if (var < 0.0) var = 0.0;
        float stdv = sqrtf((float)var);
        smu = (float)mu;
        sinv = 1.0f / (stdv + 1e-5f);
    }
    __syncthreads();
    int ci = threadIdx.x;
    if (ci < cols) {
        float A = sinv * w[ci];
        a[ci] = A;
        c[ci] = b[ci] - smu * A;
    }
}

// ---------------- fused LN2 + final GEMM [1024,512]@[512,20] + log_softmax ----------------
__global__ __launch_bounds__(64) void gemm4_lsm(const float* __restrict__ Z,
                                                const float* __restrict__ a,
                                                const float* __restrict__ c,
                                                const float* __restrict__ W,
                                                const float* __restrict__ bias,
                                                float* __restrict__ out) {
    __shared__ float zs[HID1];
    __shared__ float logits[NCLS];
    __shared__ float smax, slse;
    int m = blockIdx.x;
    for (int k = threadIdx.x; k < HID1; k += 64)
        zs[k] = Z[(size_t)m * HID1 + k] * a[k] + c[k];
    __syncthreads();
    if (threadIdx.x < NCLS) {
        float acc = bias[threadIdx.x];
        for (int k = 0; k < HID1; ++k)
            acc += zs[k] * W[k * NCLS + threadIdx.x];
        logits[threadIdx.x] = acc;
    }
    __syncthreads();
    if (threadIdx.x == 0) {
        float mx = -1e30f;
        for (int j = 0; j < NCLS; ++j) mx = fmaxf(mx, logits[j]);
        float s = 0.f;
        for (int j = 0; j < NCLS; ++j) s += expf(logits[j] - mx);
        smax = mx; slse = logf(s);
    }
    __syncthreads();
    if (threadIdx.x < NCLS)
        out[(size_t)m * NCLS + threadIdx.x] = logits[threadIdx.x] - smax - slse;
}

// ======================== launch ========================
extern "C" void kernel_launch(void* const* d_in, const int* in_sizes, int n_in,
                              void* d_out, int out_size, void* d_ws, size_t ws_size,
                              hipStream_t stream) {
    const float* x       = (const float*)d_in[0];
    const int*   ei      = (const int*)d_in[1];
    const int*   src     = ei;
    const int*   dst     = ei + NEDGES;
    const float* conv1_w = (const float*)d_in[3];
    const float* conv1_b = (const float*)d_in[4];
    const float* bn1_w   = (const float*)d_in[5];
    const float* bn1_b   = (const float*)d_in[6];
    const float* conv2_w = (const float*)d_in[7];
    const float* conv2_b = (const float*)d_in[8];
    const float* bn2_w   = (const float*)d_in[9];
    const float* bn2_b   = (const float*)d_in[10];
    const float* ln1_w   = (const float*)d_in[11];
    const float* ln1_b   = (const float*)d_in[12];
    const float* lin1_w  = (const float*)d_in[13];
    const float* lin1_b  = (const float*)d_in[14];
    const float* ln2_w   = (const float*)d_in[15];
    const float* ln2_b   = (const float*)d_in[16];
    const float* lin2_w  = (const float*)d_in[17];
    const float* lin2_b  = (const float*)d_in[18];
    float* out = (float*)d_out;

    // ---- workspace layout (peak 128 MB) ----
    char* ws = (char*)d_ws;
    const size_t KB = 1024, MB = 1048576;
    float*          dis     = (float*)(ws + 0);            // 128K
    float*          sF      = (float*)(ws + 128 * KB);     // 64K stats
    unsigned short* w1t     = (unsigned short*)(ws + 256 * KB);   // [512][128]  128K
    unsigned short* w2t     = (unsigned short*)(ws + 512 * KB);   // [1024][512] 1M
    unsigned short* w3t     = (unsigned short*)(ws + 1536 * KB);  // [512][1024] 1M
    int*            cnt     = (int*)(ws + 2560 * KB);      // 128K
    int*            offs    = (int*)(ws + 2688 * KB);      // 128K+4 (192K reserved)
    int*            cursor  = (int*)(ws + 2880 * KB);      // 128K
    int*            csr_src = (int*)(ws + 3 * MB);         // 1M
    float*          csr_w   = (float*)(ws + 4 * MB);       // 1M
    unsigned short* pool    = (unsigned short*)(ws + 5 * MB);   // [1024][1024] bf16 2M
    float*          z       = (float*)(ws + 7 * MB);       // [1024][512] f32 2M
    unsigned short* agg1    = (unsigned short*)(ws + 16 * MB);  // [N,128] bf16 8M   (16-24)
    unsigned short* h1      = (unsigned short*)(ws + 24 * MB);  // [N,512] bf16 32M  (24-56)
    unsigned short* h2      = (unsigned short*)(ws + 16 * MB);  // [N,1024] bf16 64M (16-80, overlays dead agg1+h1)
    float*          gmax    = (float*)(ws + 80 * MB);      // [G,1024] f32 4M (80-84)
    float*          gmin    = (float*)(ws + 84 * MB);      // [G,1024] f32 4M (84-88)
    unsigned short* agg2    = (unsigned short*)(ws + 88 * MB);  // [N,512] bf16 32M  (88-120)
    unsigned short* xb      = (unsigned short*)(ws + 120 * MB); // [N,128] bf16 8M  (120-128)

    float* bn1_sum = sF + 0,      *bn1_sq    = sF + 512;
    float* bn1_scale = sF + 1024, *bn1_shift = sF + 1536;
    float* bn2_sum = sF + 2048,   *bn2_sq    = sF + 3072;
    float* bn2_scale = sF + 4096, *bn2_shift = sF + 5120;
    float* ln1_a = sF + 6144, *ln1_c = sF + 7168;
    float* ln2_a = sF + 8192, *ln2_c = sF + 8704;
    double* lnacc = (double*)(sF + 9216);   // [0,1]=ln1  [2,3]=ln2

    hipMemsetAsync(sF, 0, 40960, stream);
    hipMemsetAsync(cnt, 0, NNODES * 4, stream);

    // ---- x -> bf16 ----
    f2b<<<NNODES * FIN / 8 / 256, 256, 0, stream>>>(x, xb, NNODES * FIN / 8);

    // ---- weight transposes (bf16) ----
    wtrans<<<dim3(HID1 / 64, FIN / 64),  256, 0, stream>>>(conv1_w, w1t, FIN, HID1);
    wtrans<<<dim3(HID2 / 64, HID1 / 64), 256, 0, stream>>>(conv2_w, w2t, HID1, HID2);
    wtrans<<<dim3(HID1 / 64, HID2 / 64), 256, 0, stream>>>(lin1_w,  w3t, HID2, HID1);

    // ---- CSR build (by dst) + dis ----
    csr_count<<<(NEDGES + 255) / 256, 256, 0, stream>>>(dst, cnt);
    csr_scan<<<1, 1024, 0, stream>>>(cnt, offs, cursor, dis);
    csr_fill<<<(NEDGES + 255) / 256, 256, 0, stream>>>(src, dst, dis, cursor, csr_src, csr_w);

    // ---- conv1: agg1 = A @ xb ; h1 = agg1 @ W1 + b1 (+ bn1 col stats) ----
    gcn_gather<FIN, 0><<<NNODES / 4, 256, 0, stream>>>(xb, offs, csr_src, csr_w, dis, nullptr, nullptr, agg1);
    gemm_mfma<0, 1, 1, 0><<<dim3(HID1 / 128, NNODES / 128), 256, 0, stream>>>(agg1, w1t, conv1_b, h1, bn1_sum, bn1_sq, nullptr, nullptr, NNODES, HID1, FIN);

    // ---- bn1 coeffs; conv2 gather applies BN1+ReLU on the fly ----
    bn_finalize<<<(HID1 + 255) / 256, 256, 0, stream>>>(bn1_sum, bn1_sq, bn1_w, bn1_b, bn1_scale, bn1_shift, HID1, 1.0f / NNODES);
    gcn_gather<HID1, 1><<<NNODES / 4, 256, 0, stream>>>(h1, offs, csr_src, csr_w, dis, bn1_scale, bn1_shift, agg2);
    gemm_mfma<0, 1, 1, 1><<<dim3(HID2 / 128, NNODES / 128), 256, 0, stream>>>(agg2, w2t, conv2_b, h2, bn2_sum, bn2_sq, gmax, gmin, NNODES, HID2, HID1);

    // ---- bn2 coeffs; streaming LN1 stats over relu(bn(h2)) ----
    bn_finalize<<<(HID2 + 255) / 256, 256, 0, stream>>>(bn2_sum, bn2_sq, bn2_w, bn2_b, bn2_scale, bn2_shift, HID2, 1.0f / NNODES);
    lnstats_h2<<<1024, 256, 0, stream>>>(h2, bn2_scale, bn2_shift, lnacc);

    // ---- LN1 affine + pool finalize (bn+relu+ln composed over raw max/min) ----
    ln_finalize<<<1, HID2, 0, stream>>>(lnacc, ln1_w, ln1_b, ln1_a, ln1_c, HID2, 1.0 / ((double)NNODES * HID2));
    pool_fin<<<NGRAPH * HID2 / 4 / 256, 256, 0, stream>>>(gmax, gmin, bn2_scale, bn2_shift, ln1_a, ln1_c, pool);

    // ---- lin1 + relu (MFMA, f32 out) ----
    gemm_mfma<1, 0, 0, 0><<<dim3(HID1 / 128, NGRAPH / 128), 256, 0, stream>>>(pool, w3t, lin1_b, z, nullptr, nullptr, nullptr, nullptr, NGRAPH, HID1, HID2);

    // ---- LN2 + lin2 + log_softmax ----
    global_stats<<<512, 256, 0, stream>>>(z, NGRAPH * HID1 / 4, lnacc + 2);
    ln_finalize<<<1, HID1, 0, stream>>>(lnacc + 2, ln2_w, ln2_b, ln2_a, ln2_c, HID1, 1.0 / ((double)NGRAPH * HID1));
    gemm4_lsm<<<NGRAPH, 64, 0, stream>>>(z, ln2_a, ln2_c, lin2_w, lin2_b, out);
}

// Round 10
// 276.738 us; speedup vs baseline: 1.6921x; 1.0978x over previous
//
#include <hip/hip_runtime.h>
#include <hip/hip_bf16.h>

#define NNODES 32768
#define NEDGES 262144
#define FIN    128
#define HID1   512
#define HID2   1024
#define NGRAPH 1024
#define NCLS   20

typedef __attribute__((ext_vector_type(8))) short bf16x8;
typedef __attribute__((ext_vector_type(4))) float f32x4;

// ---- bf16 bit helpers (RNE) ----
__device__ inline float bf2f(unsigned short u) {
    union { unsigned int i; float f; } v; v.i = ((unsigned int)u) << 16; return v.f;
}
__device__ inline unsigned short f2bf(float f) {
    union { unsigned int i; float f; } v; v.f = f;
    unsigned int r = v.i + 0x7FFF + ((v.i >> 16) & 1);
    return (unsigned short)(r >> 16);
}

// ---- async global -> LDS, 16B per lane ----
typedef unsigned int u32g __attribute__((address_space(1)));
typedef unsigned int u32l __attribute__((address_space(3)));
__device__ inline void load16_lds(const void* g, void* l) {
    __builtin_amdgcn_global_load_lds((const u32g*)g, (u32l*)l, 16, 0, 0);
}

// ================= workspace zero (stats + cnt) =================
__global__ __launch_bounds__(256) void zero_init(float* __restrict__ sF, int* __restrict__ cnt) {
    int t = blockIdx.x * 256 + threadIdx.x;
    if (t < 10240) sF[t] = 0.f;
    if (t < NNODES) cnt[t] = 0;
}

// ================= fp32 -> bf16 convert (x -> xb) =================
__global__ __launch_bounds__(256) void f2b(const float* __restrict__ X,
                                           unsigned short* __restrict__ Y, int total8) {
    int i = blockIdx.x * 256 + threadIdx.x;
    if (i >= total8) return;
    float4 a = ((const float4*)X)[i * 2];
    float4 b = ((const float4*)X)[i * 2 + 1];
    ushort4 u0, u1;
    u0.x = f2bf(a.x); u0.y = f2bf(a.y); u0.z = f2bf(a.z); u0.w = f2bf(a.w);
    u1.x = f2bf(b.x); u1.y = f2bf(b.y); u1.z = f2bf(b.z); u1.w = f2bf(b.w);
    ((ushort4*)Y)[i * 2] = u0;
    ((ushort4*)Y)[i * 2 + 1] = u1;
}

// ================= weight transpose + bf16 convert: Wt[n][k] = bf16(W[k][n]) =================
__global__ __launch_bounds__(256) void wtrans(const float* __restrict__ W,
                                              unsigned short* __restrict__ Wt,
                                              int K, int N) {
    __shared__ unsigned short tile[64][72];
    int kb = blockIdx.y * 64, nb = blockIdx.x * 64;
    {
        int k = threadIdx.x >> 2;
        int n0 = (threadIdx.x & 3) * 16;
#pragma unroll
        for (int q = 0; q < 4; ++q) {
            float4 v = *(const float4*)(W + (size_t)(kb + k) * N + nb + n0 + q * 4);
            tile[k][n0 + q * 4 + 0] = f2bf(v.x);
            tile[k][n0 + q * 4 + 1] = f2bf(v.y);
            tile[k][n0 + q * 4 + 2] = f2bf(v.z);
            tile[k][n0 + q * 4 + 3] = f2bf(v.w);
        }
    }
    __syncthreads();
    {
        int n = threadIdx.x >> 2;
        int k0 = (threadIdx.x & 3) * 16;
#pragma unroll
        for (int q = 0; q < 4; ++q) {
            ushort4 u;
            u.x = tile[k0 + q * 4 + 0][n];
            u.y = tile[k0 + q * 4 + 1][n];
            u.z = tile[k0 + q * 4 + 2][n];
            u.w = tile[k0 + q * 4 + 3][n];
            *(ushort4*)(Wt + (size_t)(nb + n) * K + kb + k0 + q * 4) = u;
        }
    }
}

// ================= CSR build (by dst) =================
__global__ __launch_bounds__(256) void csr_count(const int* __restrict__ dst, int* __restrict__ cnt) {
    int e = blockIdx.x * 256 + threadIdx.x;
    if (e < NEDGES) atomicAdd(&cnt[dst[e]], 1);
}

__global__ __launch_bounds__(1024) void csr_scan(const int* __restrict__ cnt,
                                                 int* __restrict__ offs,
                                                 int* __restrict__ cursor,
                                                 float* __restrict__ dis) {
    __shared__ int part[1024];
    int t = threadIdx.x;
    int base = t * 32;
    int c[32];
#pragma unroll
    for (int j = 0; j < 8; ++j) {
        int4 u = *(const int4*)(cnt + base + j * 4);
        c[j * 4 + 0] = u.x; c[j * 4 + 1] = u.y; c[j * 4 + 2] = u.z; c[j * 4 + 3] = u.w;
    }
    int s = 0;
#pragma unroll
    for (int i = 0; i < 32; ++i) s += c[i];
    part[t] = s;
    __syncthreads();
    for (int off = 1; off < 1024; off <<= 1) {
        int v = (t >= off) ? part[t - off] : 0;
        __syncthreads();
        part[t] += v;
        __syncthreads();
    }
    int run = (t == 0) ? 0 : part[t - 1];
    int ov[32]; float dv[32];
#pragma unroll
    for (int i = 0; i < 32; ++i) {
        ov[i] = run;
        dv[i] = rsqrtf((float)(c[i] + 1));
        run += c[i];
    }
#pragma unroll
    for (int j = 0; j < 8; ++j) {
        int4 o4 = make_int4(ov[j * 4], ov[j * 4 + 1], ov[j * 4 + 2], ov[j * 4 + 3]);
        *(int4*)(offs + base + j * 4) = o4;
        *(int4*)(cursor + base + j * 4) = o4;
        *(float4*)(dis + base + j * 4) = make_float4(dv[j * 4], dv[j * 4 + 1], dv[j * 4 + 2], dv[j * 4 + 3]);
    }
    if (t == 1023) offs[NNODES] = run;
}

__global__ __launch_bounds__(256) void csr_fill(const int* __restrict__ src,
                                                const int* __restrict__ dst,
                                                const float* __restrict__ dis,
                                                int* __restrict__ cursor,
                                                int* __restrict__ csr_src,
                                                float* __restrict__ csr_w) {
    int e = blockIdx.x * 256 + threadIdx.x;
    if (e >= NEDGES) return;
    int s = src[e], d = dst[e];
    int pos = atomicAdd(&cursor[d], 1);
    csr_src[pos] = s;
    csr_w[pos] = dis[s] * dis[d];
}

// ================= gather aggregation (bf16 in, bf16 out), one wave per node =================
// CPL = F/64 channels/lane; 16B int4 row loads (CPL==8) / 4B (CPL==2); 4-edge unroll.
// BNF=1: compute bn scale/shift inline from raw column sums, apply bn+relu to every row.
template<int F, int BNF>
__global__ __launch_bounds__(256) void gcn_gather(const unsigned short* __restrict__ X,
                                                  const int* __restrict__ offs,
                                                  const int* __restrict__ csr_src,
                                                  const float* __restrict__ csr_w,
                                                  const float* __restrict__ dis,
                                                  const float* __restrict__ gsum,
                                                  const float* __restrict__ gsq,
                                                  const float* __restrict__ bw,
                                                  const float* __restrict__ bb,
                                                  float invN,
                                                  unsigned short* __restrict__ out) {
    constexpr int CPL = F / 64;          // 2 (F=128) or 8 (F=512)
    int wave = threadIdx.x >> 6, lane = threadIdx.x & 63;
    int node = blockIdx.x * 4 + wave;
    int c0 = lane * CPL;
    const unsigned short* Xc = X + c0;
    float acc[CPL];
#pragma unroll
    for (int q = 0; q < CPL; ++q) acc[q] = 0.f;
    float sc[CPL], sh[CPL];
    if (BNF) {
#pragma unroll
        for (int q = 0; q < CPL; ++q) {
            int ch = c0 + q;
            float mu = gsum[ch] * invN;
            float var = gsq[ch] * invN - mu * mu;
            float s = rsqrtf(var + 1e-5f) * bw[ch];
            sc[q] = s;
            sh[q] = bb[ch] - mu * s;
        }
    }

    auto accum = [&](int s, float w) {
        if (CPL == 8) {
            int4 u = *(const int4*)(Xc + (size_t)s * F);
            const unsigned short* up = (const unsigned short*)&u;
#pragma unroll
            for (int q = 0; q < 8; ++q) {
                float v = bf2f(up[q]);
                if (BNF) v = fmaxf(v * sc[q] + sh[q], 0.f);
                acc[q] += w * v;
            }
        } else {
            ushort2 u = *(const ushort2*)(Xc + (size_t)s * F);
            float v0 = bf2f(u.x), v1 = bf2f(u.y);
            if (BNF) {
                v0 = fmaxf(v0 * sc[0] + sh[0], 0.f);
                v1 = fmaxf(v1 * sc[1] + sh[1], 0.f);
            }
            acc[0] += w * v0; acc[1] += w * v1;
        }
    };

    float sw = dis[node]; sw *= sw;
    accum(node, sw);                       // self-loop term

    int e0 = offs[node], e1 = offs[node + 1];
    int e = e0;
    for (; e + 4 <= e1; e += 4) {          // 4 independent row loads in flight
        int s0 = csr_src[e], s1 = csr_src[e + 1], s2 = csr_src[e + 2], s3 = csr_src[e + 3];
        float w0 = csr_w[e], w1 = csr_w[e + 1], w2 = csr_w[e + 2], w3 = csr_w[e + 3];
        accum(s0, w0); accum(s1, w1); accum(s2, w2); accum(s3, w3);
    }
    for (; e < e1; ++e) accum(csr_src[e], csr_w[e]);

    unsigned short* o = out + (size_t)node * F + c0;
    if (CPL == 2) {
        ushort2 u; u.x = f2bf(acc[0]); u.y = f2bf(acc[1]);
        *(ushort2*)o = u;
    } else {
        ushort4 u0, u1;
        u0.x = f2bf(acc[0]); u0.y = f2bf(acc[1]); u0.z = f2bf(acc[2]); u0.w = f2bf(acc[3]);
        u1.x = f2bf(acc[4]); u1.y = f2bf(acc[5]); u1.z = f2bf(acc[6]); u1.w = f2bf(acc[7]);
        *(ushort4*)o = u0;
        *(ushort4*)(o + 4) = u1;
    }
}

// ================= bf16 MFMA GEMM: C[M][N] = A[M][K] @ B (Bt[N][K]) =================
// 128x128 tile, BK=64, 4 waves. global_load_lds staging; LDS XOR-swizzle via pre-swizzled source.
// CBF16=1: LDS-staged coalesced bf16 store. STATS=1: fused per-column sum/sumsq atomics.
// POOL=1: per-graph (32 rows) per-column raw max/min. GSTATS=1 (f32 path): fused global sum/sumsq.
template<int EPI, int CBF16, int STATS, int POOL, int GSTATS>
__global__ __launch_bounds__(256, 2) void gemm_mfma(const unsigned short* __restrict__ A,
                                                    const unsigned short* __restrict__ Bt,
                                                    const float* __restrict__ bias,
                                                    void* __restrict__ Cv,
                                                    float* __restrict__ gsum,
                                                    float* __restrict__ gsq,
                                                    float* __restrict__ gmax,
                                                    float* __restrict__ gmin,
                                                    double* __restrict__ gacc,
                                                    int M, int N, int K) {
    constexpr int BM = 128, BN = 128, BK = 64;
    __shared__ unsigned short smem[128 * 136];
    unsigned short* As = smem;
    unsigned short* Bs = smem + BM * BK;

    const int tid = threadIdx.x;
    const int lane = tid & 63;
    const int wave = tid >> 6;
    const int wr = wave >> 1, wc = wave & 1;

    const int nwg = gridDim.x * gridDim.y;
    const int wg = blockIdx.y * gridDim.x + blockIdx.x;
    const int cpx = nwg >> 3;
    const int swz = (wg & 7) * cpx + (wg >> 3);
    const int m0 = (swz / gridDim.x) * BM, n0 = (swz % gridDim.x) * BN;

    const int sub = ((tid & 7) * 16) ^ (((tid >> 3) & 7) << 4);
    const int rbase = tid >> 3;
    const char* Ab = (const char*)A + sub;
    const char* Bb = (const char*)Bt + sub;

    f32x4 acc[4][4] = {};

    for (int k0 = 0; k0 < K; k0 += BK) {
        __syncthreads();
#pragma unroll
        for (int i = 0; i < 4; ++i) {
            int r = i * 32 + rbase;
            load16_lds(Ab + ((size_t)(m0 + r) * K + k0) * 2, (char*)As + i * 4096 + tid * 16);
            load16_lds(Bb + ((size_t)(n0 + r) * K + k0) * 2, (char*)Bs + i * 4096 + tid * 16);
        }
        __syncthreads();
#pragma unroll
        for (int ks = 0; ks < 2; ++ks) {
            bf16x8 af[4], bfr[4];
#pragma unroll
            for (int m = 0; m < 4; ++m) {
                int row = wr * 64 + m * 16 + (lane & 15);
                int s = (ks * 64 + ((lane >> 4) * 16)) ^ ((row & 7) << 4);
                af[m] = *(const bf16x8*)((const char*)As + row * 128 + s);
            }
#pragma unroll
            for (int n = 0; n < 4; ++n) {
                int row = wc * 64 + n * 16 + (lane & 15);
                int s = (ks * 64 + ((lane >> 4) * 16)) ^ ((row & 7) << 4);
                bfr[n] = *(const bf16x8*)((const char*)Bs + row * 128 + s);
            }
#pragma unroll
            for (int m = 0; m < 4; ++m)
#pragma unroll
                for (int n = 0; n < 4; ++n)
                    acc[m][n] = __builtin_amdgcn_mfma_f32_16x16x32_bf16(af[m], bfr[n], acc[m][n], 0, 0, 0);
        }
    }

    // ---- epilogue ----
    if (CBF16) {
        __syncthreads();
        float cs[4], cq[4];
        float pmx[2][4], pmn[2][4];
#pragma unroll
        for (int n = 0; n < 4; ++n) {
            cs[n] = 0.f; cq[n] = 0.f;
            if (POOL) {
                pmx[0][n] = -1e30f; pmx[1][n] = -1e30f;
                pmn[0][n] = 1e30f;  pmn[1][n] = 1e30f;
            }
        }
#pragma unroll
        for (int n = 0; n < 4; ++n) {
            int col = wc * 64 + n * 16 + (lane & 15);
            float bsv = bias[n0 + col];
#pragma unroll
            for (int m = 0; m < 4; ++m) {
                int rbase2 = wr * 64 + m * 16 + ((lane >> 4) << 2);
#pragma unroll
                for (int j = 0; j < 4; ++j) {
                    float v = acc[m][n][j] + bsv;
                    if (STATS) { cs[n] += v; cq[n] += v * v; }
                    if (POOL) {
                        pmx[m >> 1][n] = fmaxf(pmx[m >> 1][n], v);
                        pmn[m >> 1][n] = fminf(pmn[m >> 1][n], v);
                    }
                    if (EPI == 1) v = fmaxf(v, 0.f);
                    smem[(rbase2 + j) * 136 + col] = f2bf(v);
                }
            }
        }
        if (STATS) {
#pragma unroll
            for (int n = 0; n < 4; ++n) {
                cs[n] += __shfl_xor(cs[n], 16); cs[n] += __shfl_xor(cs[n], 32);
                cq[n] += __shfl_xor(cq[n], 16); cq[n] += __shfl_xor(cq[n], 32);
            }
            if (lane < 16) {
#pragma unroll
                for (int n = 0; n < 4; ++n) {
                    int col = n0 + wc * 64 + n * 16 + lane;
                    atomicAdd(&gsum[col], cs[n]);
                    atomicAdd(&gsq[col],  cq[n]);
                }
            }
        }
        if (POOL) {
#pragma unroll
            for (int gi = 0; gi < 2; ++gi)
#pragma unroll
                for (int n = 0; n < 4; ++n) {
                    pmx[gi][n] = fmaxf(pmx[gi][n], __shfl_xor(pmx[gi][n], 16));
                    pmx[gi][n] = fmaxf(pmx[gi][n], __shfl_xor(pmx[gi][n], 32));
                    pmn[gi][n] = fminf(pmn[gi][n], __shfl_xor(pmn[gi][n], 16));
                    pmn[gi][n] = fminf(pmn[gi][n], __shfl_xor(pmn[gi][n], 32));
                }
            if (lane < 16) {
                int gb = (m0 >> 5) + wr * 2;
#pragma unroll
                for (int gi = 0; gi < 2; ++gi)
#pragma unroll
                    for (int n = 0; n < 4; ++n) {
                        int col = n0 + wc * 64 + n * 16 + lane;
                        gmax[(size_t)(gb + gi) * HID2 + col] = pmx[gi][n];
                        gmin[(size_t)(gb + gi) * HID2 + col] = pmn[gi][n];
                    }
            }
        }
        __syncthreads();
#pragma unroll
        for (int it = 0; it < 8; ++it) {
            int r = it * 16 + (tid >> 4);
            int ch = tid & 15;
            int4 v = *(const int4*)&smem[r * 136 + ch * 8];
            *(int4*)((unsigned short*)Cv + (size_t)(m0 + r) * N + n0 + ch * 8) = v;
        }
    } else {
        float ls = 0.f, lq = 0.f;
#pragma unroll
        for (int m = 0; m < 4; ++m) {
            int row = m0 + wr * 64 + m * 16 + ((lane >> 4) << 2);
#pragma unroll
            for (int n = 0; n < 4; ++n) {
                int col = n0 + wc * 64 + n * 16 + (lane & 15);
                float bsv = bias[col];
#pragma unroll
                for (int j = 0; j < 4; ++j) {
                    float v = acc[m][n][j] + bsv;
                    if (EPI == 1) v = fmaxf(v, 0.f);
                    if (GSTATS) { ls += v; lq += v * v; }
                    ((float*)Cv)[(size_t)(row + j) * N + col] = v;
                }
            }
        }
        if (GSTATS) {
            for (int o = 32; o > 0; o >>= 1) {
                ls += __shfl_down(ls, o);
                lq += __shfl_down(lq, o);
            }
            if (lane == 0) {
                atomicAdd(gacc,     (double)ls);
                atomicAdd(gacc + 1, (double)lq);
            }
        }
    }
}

// ---------------- streaming LN1 stats of relu(bn(h2)); bn2 coeffs computed inline ----------------
__global__ __launch_bounds__(256) void lnstats_h2(const unsigned short* __restrict__ H,
                                                  const float* __restrict__ gsum,
                                                  const float* __restrict__ gsq,
                                                  const float* __restrict__ bw,
                                                  const float* __restrict__ bb,
                                                  float invN,
                                                  double* __restrict__ lnacc) {
    int half = threadIdx.x >> 7;              // 0..1
    int c0 = (threadIdx.x & 127) * 8;
    float sc[8], sh[8];
#pragma unroll
    for (int q = 0; q < 8; ++q) {
        int ch = c0 + q;
        float mu = gsum[ch] * invN;
        float var = gsq[ch] * invN - mu * mu;
        float s = rsqrtf(var + 1e-5f) * bw[ch];
        sc[q] = s;
        sh[q] = bb[ch] - mu * s;
    }
    float lsum = 0.f, lsq = 0.f;
    for (int r = blockIdx.x * 2 + half; r < NNODES; r += gridDim.x * 2) {
        int4 u = *(const int4*)(H + (size_t)r * HID2 + c0);
        const unsigned short* up = (const unsigned short*)&u;
#pragma unroll
        for (int q = 0; q < 8; ++q) {
            float v = fmaxf(bf2f(up[q]) * sc[q] + sh[q], 0.f);
            lsum += v; lsq += v * v;
        }
    }
    for (int o = 32; o > 0; o >>= 1) {
        lsum += __shfl_down(lsum, o);
        lsq  += __shfl_down(lsq, o);
    }
    __shared__ float w1[4], w2[4];
    int wid = threadIdx.x >> 6, lane = threadIdx.x & 63;
    if (lane == 0) { w1[wid] = lsum; w2[wid] = lsq; }
    __syncthreads();
    if (threadIdx.x == 0) {
        atomicAdd(lnacc,     (double)(w1[0] + w1[1] + w1[2] + w1[3]));
        atomicAdd(lnacc + 1, (double)(w2[0] + w2[1] + w2[2] + w2[3]));
    }
}

// ---------------- pool finalize: compose bn+relu+ln over raw max/min; all coeffs inline ----------------
__global__ __launch_bounds__(256) void pool_fin(const float* __restrict__ gmax,
                                                const float* __restrict__ gmin,
                                                const float* __restrict__ bsum,
                                                const float* __restrict__ bsq,
                                                const float* __restrict__ bw,
                                                const float* __restrict__ bb,
                                                const double* __restrict__ lnacc,
                                                const float* __restrict__ lw,
                                                const float* __restrict__ lb,
                                                float invN, double invCnt,
                                                unsigned short* __restrict__ P) {
    int i = blockIdx.x * 256 + threadIdx.x;            // over NGRAPH*HID2/4
    int c0 = (i * 4) & (HID2 - 1);
    double dmu = lnacc[0] * invCnt;
    double dvar = lnacc[1] * invCnt - dmu * dmu;
    if (dvar < 0.0) dvar = 0.0;
    float smu = (float)dmu;
    float sinv = 1.0f / (sqrtf((float)dvar) + 1e-5f);
    float4 mx = ((const float4*)gmax)[i];
    float4 mn = ((const float4*)gmin)[i];
    float r[4];
    const float* mxp = (const float*)&mx;
    const float* mnp = (const float*)&mn;
#pragma unroll
    for (int q = 0; q < 4; ++q) {
        int ch = c0 + q;
        float bmu = bsum[ch] * invN;
        float bvar = bsq[ch] * invN - bmu * bmu;
        float s = rsqrtf(bvar + 1e-5f) * bw[ch];
        float t = bb[ch] - bmu * s;
        float A = sinv * lw[ch];
        float C = lb[ch] - smu * A;
        float vs = ((s >= 0.f) == (A >= 0.f)) ? mxp[q] : mnp[q];
        r[q] = A * fmaxf(s * vs + t, 0.f) + C;
    }
    ushort4 o;
    o.x = f2bf(r[0]); o.y = f2bf(r[1]); o.z = f2bf(r[2]); o.w = f2bf(r[3]);
    ((ushort4*)P)[i] = o;
}

// ---------------- fused LN2 (inline coeffs) + final GEMM [1024,512]@[512,20] + log_softmax ----------------
__global__ __launch_bounds__(64) void gemm4_lsm(const float* __restrict__ Z,
                                                const double* __restrict__ acc2,
                                                const float* __restrict__ lw,
                                                const float* __restrict__ lb,
                                                const float* __restrict__ W,
                                                const float* __restrict__ bias,
                                                double invCnt,
                                                float* __restrict__ out) {
    __shared__ float zs[HID1];
    __shared__ float logits[NCLS];
    __shared__ float smaxs, slse;
    int m = blockIdx.x;
    double dmu = acc2[0] * invCnt;
    double dvar = acc2[1] * invCnt - dmu * dmu;
    if (dvar < 0.0) dvar = 0.0;
    float smu = (float)dmu;
    float sinv = 1.0f / (sqrtf((float)dvar) + 1e-5f);
    for (int k = threadIdx.x; k < HID1; k += 64) {
        float A = sinv * lw[k];
        zs[k] = Z[(size_t)m * HID1 + k] * A + (lb[k] - smu * A);
    }
    __syncthreads();
    if (threadIdx.x < NCLS) {
        float acc = bias[threadIdx.x];
        for (int k = 0; k < HID1; ++k)
            acc += zs[k] * W[k * NCLS + threadIdx.x];
        logits[threadIdx.x] = acc;
    }
    __syncthreads();
    if (threadIdx.x == 0) {
        float mx = -1e30f;
        for (int j = 0; j < NCLS; ++j) mx = fmaxf(mx, logits[j]);
        float s = 0.f;
        for (int j = 0; j < NCLS; ++j) s += expf(logits[j] - mx);
        smaxs = mx; slse = logf(s);
    }
    __syncthreads();
    if (threadIdx.x < NCLS)
        out[(size_t)m * NCLS + threadIdx.x] = logits[threadIdx.x] - smaxs - slse;
}

// ======================== launch ========================
extern "C" void kernel_launch(void* const* d_in, const int* in_sizes, int n_in,
                              void* d_out, int out_size, void* d_ws, size_t ws_size,
                              hipStream_t stream) {
    const float* x       = (const float*)d_in[0];
    const int*   ei      = (const int*)d_in[1];
    const int*   src     = ei;
    const int*   dst     = ei + NEDGES;
    const float* conv1_w = (const float*)d_in[3];
    const float* conv1_b = (const float*)d_in[4];
    const float* bn1_w   = (const float*)d_in[5];
    const float* bn1_b   = (const float*)d_in[6];
    const float* conv2_w = (const float*)d_in[7];
    const float* conv2_b = (const float*)d_in[8];
    const float* bn2_w   = (const float*)d_in[9];
    const float* bn2_b   = (const float*)d_in[10];
    const float* ln1_w   = (const float*)d_in[11];
    const float* ln1_b   = (const float*)d_in[12];
    const float* lin1_w  = (const float*)d_in[13];
    const float* lin1_b  = (const float*)d_in[14];
    const float* ln2_w   = (const float*)d_in[15];
    const float* ln2_b   = (const float*)d_in[16];
    const float* lin2_w  = (const float*)d_in[17];
    const float* lin2_b  = (const float*)d_in[18];
    float* out = (float*)d_out;

    // ---- workspace layout (peak 128 MB) ----
    char* ws = (char*)d_ws;
    const size_t KB = 1024, MB = 1048576;
    float*          dis     = (float*)(ws + 0);            // 128K
    float*          sF      = (float*)(ws + 128 * KB);     // 40K stats
    unsigned short* w1t     = (unsigned short*)(ws + 256 * KB);   // [512][128]  128K
    unsigned short* w2t     = (unsigned short*)(ws + 512 * KB);   // [1024][512] 1M
    unsigned short* w3t     = (unsigned short*)(ws + 1536 * KB);  // [512][1024] 1M
    int*            cnt     = (int*)(ws + 2560 * KB);      // 128K
    int*            offs    = (int*)(ws + 2688 * KB);      // 128K+4 (192K reserved)
    int*            cursor  = (int*)(ws + 2880 * KB);      // 128K
    int*            csr_src = (int*)(ws + 3 * MB);         // 1M
    float*          csr_w   = (float*)(ws + 4 * MB);       // 1M
    unsigned short* pool    = (unsigned short*)(ws + 5 * MB);   // [1024][1024] bf16 2M
    float*          z       = (float*)(ws + 7 * MB);       // [1024][512] f32 2M
    unsigned short* agg1    = (unsigned short*)(ws + 16 * MB);  // [N,128] bf16 8M   (16-24)
    unsigned short* h1      = (unsigned short*)(ws + 24 * MB);  // [N,512] bf16 32M  (24-56)
    unsigned short* h2      = (unsigned short*)(ws + 16 * MB);  // [N,1024] bf16 64M (16-80)
    float*          gmax    = (float*)(ws + 80 * MB);      // [G,1024] f32 4M (80-84)
    float*          gmin    = (float*)(ws + 84 * MB);      // [G,1024] f32 4M (84-88)
    unsigned short* agg2    = (unsigned short*)(ws + 88 * MB);  // [N,512] bf16 32M  (88-120)
    unsigned short* xb      = (unsigned short*)(ws + 120 * MB); // [N,128] bf16 8M  (120-128)

    float* bn1_sum = sF + 0,      *bn1_sq    = sF + 512;
    float* bn2_sum = sF + 2048,   *bn2_sq    = sF + 3072;
    double* lnacc = (double*)(sF + 9216);   // [0,1]=ln1  [2,3]=ln2

    const float invN = 1.0f / (float)NNODES;

    // ---- zero stats + cnt (one dispatch) ----
    zero_init<<<128, 256, 0, stream>>>(sF, cnt);

    // ---- x -> bf16 ----
    f2b<<<NNODES * FIN / 8 / 256, 256, 0, stream>>>(x, xb, NNODES * FIN / 8);

    // ---- weight transposes (bf16) ----
    wtrans<<<dim3(HID1 / 64, FIN / 64),  256, 0, stream>>>(conv1_w, w1t, FIN, HID1);
    wtrans<<<dim3(HID2 / 64, HID1 / 64), 256, 0, stream>>>(conv2_w, w2t, HID1, HID2);
    wtrans<<<dim3(HID1 / 64, HID2 / 64), 256, 0, stream>>>(lin1_w,  w3t, HID2, HID1);

    // ---- CSR build (by dst) + dis ----
    csr_count<<<(NEDGES + 255) / 256, 256, 0, stream>>>(dst, cnt);
    csr_scan<<<1, 1024, 0, stream>>>(cnt, offs, cursor, dis);
    csr_fill<<<(NEDGES + 255) / 256, 256, 0, stream>>>(src, dst, dis, cursor, csr_src, csr_w);

    // ---- conv1: agg1 = A @ xb ; h1 = agg1 @ W1 + b1 (+ bn1 col stats) ----
    gcn_gather<FIN, 0><<<NNODES / 4, 256, 0, stream>>>(xb, offs, csr_src, csr_w, dis,
                                                       nullptr, nullptr, nullptr, nullptr, 0.f, agg1);
    gemm_mfma<0, 1, 1, 0, 0><<<dim3(HID1 / 128, NNODES / 128), 256, 0, stream>>>(
        agg1, w1t, conv1_b, h1, bn1_sum, bn1_sq, nullptr, nullptr, nullptr, NNODES, HID1, FIN);

    // ---- conv2: gather applies bn1+relu (coeffs inline from raw sums) ----
    gcn_gather<HID1, 1><<<NNODES / 4, 256, 0, stream>>>(h1, offs, csr_src, csr_w, dis,
                                                        bn1_sum, bn1_sq, bn1_w, bn1_b, invN, agg2);
    gemm_mfma<0, 1, 1, 1, 0><<<dim3(HID2 / 128, NNODES / 128), 256, 0, stream>>>(
        agg2, w2t, conv2_b, h2, bn2_sum, bn2_sq, gmax, gmin, nullptr, NNODES, HID2, HID1);

    // ---- streaming LN1 stats over relu(bn2(h2)) (bn2 coeffs inline) ----
    lnstats_h2<<<1024, 256, 0, stream>>>(h2, bn2_sum, bn2_sq, bn2_w, bn2_b, invN, lnacc);

    // ---- pool finalize (bn2+relu+ln1 composed over raw max/min; all coeffs inline) ----
    pool_fin<<<NGRAPH * HID2 / 4 / 256, 256, 0, stream>>>(
        gmax, gmin, bn2_sum, bn2_sq, bn2_w, bn2_b, lnacc, ln1_w, ln1_b,
        invN, 1.0 / ((double)NNODES * HID2), pool);

    // ---- lin1 + relu (MFMA, f32 out, fused LN2 global stats) ----
    gemm_mfma<1, 0, 0, 0, 1><<<dim3(HID1 / 128, NGRAPH / 128), 256, 0, stream>>>(
        pool, w3t, lin1_b, z, nullptr, nullptr, nullptr, nullptr, lnacc + 2, NGRAPH, HID1, HID2);

    // ---- LN2 (inline) + lin2 + log_softmax ----
    gemm4_lsm<<<NGRAPH, 64, 0, stream>>>(z, lnacc + 2, ln2_w, ln2_b, lin2_w, lin2_b,
                                         1.0 / ((double)NGRAPH * HID1), out);
}

// Round 11
// 267.147 us; speedup vs baseline: 1.7528x; 1.0359x over previous
//
#include <hip/hip_runtime.h>
#include <hip/hip_bf16.h>

#define NNODES 32768
#define NEDGES 262144
#define FIN    128
#define HID1   512
#define HID2   1024
#define NGRAPH 1024
#define NCLS   20

typedef __attribute__((ext_vector_type(8))) short bf16x8;
typedef __attribute__((ext_vector_type(4))) float f32x4;

// ---- bf16 bit helpers (RNE) ----
__device__ inline float bf2f(unsigned short u) {
    union { unsigned int i; float f; } v; v.i = ((unsigned int)u) << 16; return v.f;
}
__device__ inline unsigned short f2bf(float f) {
    union { unsigned int i; float f; } v; v.f = f;
    unsigned int r = v.i + 0x7FFF + ((v.i >> 16) & 1);
    return (unsigned short)(r >> 16);
}

// ---- async global -> LDS, 16B per lane ----
typedef unsigned int u32g __attribute__((address_space(1)));
typedef unsigned int u32l __attribute__((address_space(3)));
__device__ inline void load16_lds(const void* g, void* l) {
    __builtin_amdgcn_global_load_lds((const u32g*)g, (u32l*)l, 16, 0, 0);
}

// ================= fused prologue: zero ∪ f2b ∪ wtrans×3 (blockIdx-partitioned) =================
__device__ inline void wtrans_body(const float* __restrict__ W, unsigned short* __restrict__ Wt,
                                   int K, int N, int bx, int by, unsigned short (*tile)[72]) {
    int kb = by * 64, nb = bx * 64;
    {
        int k = threadIdx.x >> 2;
        int n0 = (threadIdx.x & 3) * 16;
#pragma unroll
        for (int q = 0; q < 4; ++q) {
            float4 v = *(const float4*)(W + (size_t)(kb + k) * N + nb + n0 + q * 4);
            tile[k][n0 + q * 4 + 0] = f2bf(v.x);
            tile[k][n0 + q * 4 + 1] = f2bf(v.y);
            tile[k][n0 + q * 4 + 2] = f2bf(v.z);
            tile[k][n0 + q * 4 + 3] = f2bf(v.w);
        }
    }
    __syncthreads();
    {
        int n = threadIdx.x >> 2;
        int k0 = (threadIdx.x & 3) * 16;
#pragma unroll
        for (int q = 0; q < 4; ++q) {
            ushort4 u;
            u.x = tile[k0 + q * 4 + 0][n];
            u.y = tile[k0 + q * 4 + 1][n];
            u.z = tile[k0 + q * 4 + 2][n];
            u.w = tile[k0 + q * 4 + 3][n];
            *(ushort4*)(Wt + (size_t)(nb + n) * K + kb + k0 + q * 4) = u;
        }
    }
}

// block ranges: [0,168) zero | [168,2216) f2b | [2216,2232) w1 | [2232,2360) w2 | [2360,2488) w3
__global__ __launch_bounds__(256) void prep(const float* __restrict__ x, unsigned short* __restrict__ xb,
                                            const float* __restrict__ W1, unsigned short* __restrict__ w1t,
                                            const float* __restrict__ W2, unsigned short* __restrict__ w2t,
                                            const float* __restrict__ W3, unsigned short* __restrict__ w3t,
                                            float* __restrict__ sF, int* __restrict__ cnt) {
    __shared__ unsigned short tile[64][72];
    int b = blockIdx.x;
    if (b < 168) {
        int t = b * 256 + threadIdx.x;
        if (t < 10240) sF[t] = 0.f;
        if (t < NNODES) cnt[t] = 0;
    } else if (b < 2216) {
        int i = (b - 168) * 256 + threadIdx.x;   // < 524288
        float4 a = ((const float4*)x)[i * 2];
        float4 c = ((const float4*)x)[i * 2 + 1];
        ushort4 u0, u1;
        u0.x = f2bf(a.x); u0.y = f2bf(a.y); u0.z = f2bf(a.z); u0.w = f2bf(a.w);
        u1.x = f2bf(c.x); u1.y = f2bf(c.y); u1.z = f2bf(c.z); u1.w = f2bf(c.w);
        ((ushort4*)xb)[i * 2] = u0;
        ((ushort4*)xb)[i * 2 + 1] = u1;
    } else if (b < 2232) {
        int q = b - 2216;                         // 16 blocks: bx 8, by 2
        wtrans_body(W1, w1t, FIN, HID1, q & 7, q >> 3, tile);
    } else if (b < 2360) {
        int q = b - 2232;                         // 128 blocks: bx 16, by 8
        wtrans_body(W2, w2t, HID1, HID2, q & 15, q >> 4, tile);
    } else {
        int q = b - 2360;                         // 128 blocks: bx 8, by 16
        wtrans_body(W3, w3t, HID2, HID1, q & 7, q >> 3, tile);
    }
}

// ================= CSR build (by dst), interleaved {src, w} =================
__global__ __launch_bounds__(256) void csr_count(const int* __restrict__ dst, int* __restrict__ cnt) {
    int e = blockIdx.x * 256 + threadIdx.x;
    if (e < NEDGES) atomicAdd(&cnt[dst[e]], 1);
}

__global__ __launch_bounds__(1024) void csr_scan(const int* __restrict__ cnt,
                                                 int* __restrict__ offs,
                                                 int* __restrict__ cursor,
                                                 float* __restrict__ dis) {
    __shared__ int part[1024];
    int t = threadIdx.x;
    int base = t * 32;
    int c[32];
#pragma unroll
    for (int j = 0; j < 8; ++j) {
        int4 u = *(const int4*)(cnt + base + j * 4);
        c[j * 4 + 0] = u.x; c[j * 4 + 1] = u.y; c[j * 4 + 2] = u.z; c[j * 4 + 3] = u.w;
    }
    int s = 0;
#pragma unroll
    for (int i = 0; i < 32; ++i) s += c[i];
    part[t] = s;
    __syncthreads();
    for (int off = 1; off < 1024; off <<= 1) {
        int v = (t >= off) ? part[t - off] : 0;
        __syncthreads();
        part[t] += v;
        __syncthreads();
    }
    int run = (t == 0) ? 0 : part[t - 1];
    int ov[32]; float dv[32];
#pragma unroll
    for (int i = 0; i < 32; ++i) {
        ov[i] = run;
        dv[i] = rsqrtf((float)(c[i] + 1));
        run += c[i];
    }
#pragma unroll
    for (int j = 0; j < 8; ++j) {
        int4 o4 = make_int4(ov[j * 4], ov[j * 4 + 1], ov[j * 4 + 2], ov[j * 4 + 3]);
        *(int4*)(offs + base + j * 4) = o4;
        *(int4*)(cursor + base + j * 4) = o4;
        *(float4*)(dis + base + j * 4) = make_float4(dv[j * 4], dv[j * 4 + 1], dv[j * 4 + 2], dv[j * 4 + 3]);
    }
    if (t == 1023) offs[NNODES] = run;
}

__global__ __launch_bounds__(256) void csr_fill(const int* __restrict__ src,
                                                const int* __restrict__ dst,
                                                const float* __restrict__ dis,
                                                int* __restrict__ cursor,
                                                int2* __restrict__ csr_e) {
    int e = blockIdx.x * 256 + threadIdx.x;
    if (e >= NEDGES) return;
    int s = src[e], d = dst[e];
    int pos = atomicAdd(&cursor[d], 1);
    int2 v; v.x = s; v.y = __float_as_int(dis[s] * dis[d]);
    csr_e[pos] = v;
}

// ================= gather aggregation (bf16 in, bf16 out), one wave per node =================
// CPL = F/64 channels/lane; 16B int4 row loads (CPL==8) / 4B (CPL==2); 8-edge unroll (8 loads in flight).
// BNF=1: compute bn scale/shift inline from raw column sums, apply bn+relu to every row.
template<int F, int BNF>
__global__ __launch_bounds__(256) void gcn_gather(const unsigned short* __restrict__ X,
                                                  const int* __restrict__ offs,
                                                  const int2* __restrict__ csr_e,
                                                  const float* __restrict__ dis,
                                                  const float* __restrict__ gsum,
                                                  const float* __restrict__ gsq,
                                                  const float* __restrict__ bw,
                                                  const float* __restrict__ bb,
                                                  float invN,
                                                  unsigned short* __restrict__ out) {
    constexpr int CPL = F / 64;          // 2 (F=128) or 8 (F=512)
    int wave = threadIdx.x >> 6, lane = threadIdx.x & 63;
    int node = blockIdx.x * 4 + wave;
    int c0 = lane * CPL;
    const unsigned short* Xc = X + c0;
    float acc[CPL];
#pragma unroll
    for (int q = 0; q < CPL; ++q) acc[q] = 0.f;
    float sc[CPL], sh[CPL];
    if (BNF) {
#pragma unroll
        for (int q = 0; q < CPL; ++q) {
            int ch = c0 + q;
            float mu = gsum[ch] * invN;
            float var = gsq[ch] * invN - mu * mu;
            float s = rsqrtf(var + 1e-5f) * bw[ch];
            sc[q] = s;
            sh[q] = bb[ch] - mu * s;
        }
    }

    auto accum = [&](int s, float w) {
        if (CPL == 8) {
            int4 u = *(const int4*)(Xc + (size_t)s * F);
            const unsigned short* up = (const unsigned short*)&u;
#pragma unroll
            for (int q = 0; q < 8; ++q) {
                float v = bf2f(up[q]);
                if (BNF) v = fmaxf(v * sc[q] + sh[q], 0.f);
                acc[q] += w * v;
            }
        } else {
            ushort2 u = *(const ushort2*)(Xc + (size_t)s * F);
            float v0 = bf2f(u.x), v1 = bf2f(u.y);
            if (BNF) {
                v0 = fmaxf(v0 * sc[0] + sh[0], 0.f);
                v1 = fmaxf(v1 * sc[1] + sh[1], 0.f);
            }
            acc[0] += w * v0; acc[1] += w * v1;
        }
    };

    float sw = dis[node]; sw *= sw;
    accum(node, sw);                       // self-loop term

    int e0 = offs[node], e1 = offs[node + 1];
    int e = e0;
    for (; e + 8 <= e1; e += 8) {          // 8 independent row loads in flight
        int2 ed[8];
#pragma unroll
        for (int j = 0; j < 8; ++j) ed[j] = csr_e[e + j];
#pragma unroll
        for (int j = 0; j < 8; ++j) accum(ed[j].x, __int_as_float(ed[j].y));
    }
    for (; e + 4 <= e1; e += 4) {
        int2 ed[4];
#pragma unroll
        for (int j = 0; j < 4; ++j) ed[j] = csr_e[e + j];
#pragma unroll
        for (int j = 0; j < 4; ++j) accum(ed[j].x, __int_as_float(ed[j].y));
    }
    for (; e < e1; ++e) {
        int2 ed = csr_e[e];
        accum(ed.x, __int_as_float(ed.y));
    }

    unsigned short* o = out + (size_t)node * F + c0;
    if (CPL == 2) {
        ushort2 u; u.x = f2bf(acc[0]); u.y = f2bf(acc[1]);
        *(ushort2*)o = u;
    } else {
        ushort4 u0, u1;
        u0.x = f2bf(acc[0]); u0.y = f2bf(acc[1]); u0.z = f2bf(acc[2]); u0.w = f2bf(acc[3]);
        u1.x = f2bf(acc[4]); u1.y = f2bf(acc[5]); u1.z = f2bf(acc[6]); u1.w = f2bf(acc[7]);
        *(ushort4*)o = u0;
        *(ushort4*)(o + 4) = u1;
    }
}

// ================= bf16 MFMA GEMM: C[M][N] = A[M][K] @ B (Bt[N][K]) =================
// 128x128 tile, BK=64, 4 waves. global_load_lds staging; LDS XOR-swizzle via pre-swizzled source.
// CBF16=1: LDS-staged coalesced bf16 store. STATS=1: fused per-column sum/sumsq atomics.
// POOL=1: per-graph (32 rows) per-column raw max/min. GSTATS=1 (f32 path): fused global sum/sumsq.
template<int EPI, int CBF16, int STATS, int POOL, int GSTATS>
__global__ __launch_bounds__(256, 2) void gemm_mfma(const unsigned short* __restrict__ A,
                                                    const unsigned short* __restrict__ Bt,
                                                    const float* __restrict__ bias,
                                                    void* __restrict__ Cv,
                                                    float* __restrict__ gsum,
                                                    float* __restrict__ gsq,
                                                    float* __restrict__ gmax,
                                                    float* __restrict__ gmin,
                                                    double* __restrict__ gacc,
                                                    int M, int N, int K) {
    constexpr int BM = 128, BN = 128, BK = 64;
    __shared__ unsigned short smem[128 * 136];
    unsigned short* As = smem;
    unsigned short* Bs = smem + BM * BK;

    const int tid = threadIdx.x;
    const int lane = tid & 63;
    const int wave = tid >> 6;
    const int wr = wave >> 1, wc = wave & 1;

    const int nwg = gridDim.x * gridDim.y;
    const int wg = blockIdx.y * gridDim.x + blockIdx.x;
    const int cpx = nwg >> 3;
    const int swz = (wg & 7) * cpx + (wg >> 3);
    const int m0 = (swz / gridDim.x) * BM, n0 = (swz % gridDim.x) * BN;

    const int sub = ((tid & 7) * 16) ^ (((tid >> 3) & 7) << 4);
    const int rbase = tid >> 3;
    const char* Ab = (const char*)A + sub;
    const char* Bb = (const char*)Bt + sub;

    f32x4 acc[4][4] = {};

    for (int k0 = 0; k0 < K; k0 += BK) {
        __syncthreads();
#pragma unroll
        for (int i = 0; i < 4; ++i) {
            int r = i * 32 + rbase;
            load16_lds(Ab + ((size_t)(m0 + r) * K + k0) * 2, (char*)As + i * 4096 + tid * 16);
            load16_lds(Bb + ((size_t)(n0 + r) * K + k0) * 2, (char*)Bs + i * 4096 + tid * 16);
        }
        __syncthreads();
#pragma unroll
        for (int ks = 0; ks < 2; ++ks) {
            bf16x8 af[4], bfr[4];
#pragma unroll
            for (int m = 0; m < 4; ++m) {
                int row = wr * 64 + m * 16 + (lane & 15);
                int s = (ks * 64 + ((lane >> 4) * 16)) ^ ((row & 7) << 4);
                af[m] = *(const bf16x8*)((const char*)As + row * 128 + s);
            }
#pragma unroll
            for (int n = 0; n < 4; ++n) {
                int row = wc * 64 + n * 16 + (lane & 15);
                int s = (ks * 64 + ((lane >> 4) * 16)) ^ ((row & 7) << 4);
                bfr[n] = *(const bf16x8*)((const char*)Bs + row * 128 + s);
            }
#pragma unroll
            for (int m = 0; m < 4; ++m)
#pragma unroll
                for (int n = 0; n < 4; ++n)
                    acc[m][n] = __builtin_amdgcn_mfma_f32_16x16x32_bf16(af[m], bfr[n], acc[m][n], 0, 0, 0);
        }
    }

    // ---- epilogue ----
    if (CBF16) {
        __syncthreads();
        float cs[4], cq[4];
        float pmx[2][4], pmn[2][4];
#pragma unroll
        for (int n = 0; n < 4; ++n) {
            cs[n] = 0.f; cq[n] = 0.f;
            if (POOL) {
                pmx[0][n] = -1e30f; pmx[1][n] = -1e30f;
                pmn[0][n] = 1e30f;  pmn[1][n] = 1e30f;
            }
        }
#pragma unroll
        for (int n = 0; n < 4; ++n) {
            int col = wc * 64 + n * 16 + (lane & 15);
            float bsv = bias[n0 + col];
#pragma unroll
            for (int m = 0; m < 4; ++m) {
                int rbase2 = wr * 64 + m * 16 + ((lane >> 4) << 2);
#pragma unroll
                for (int j = 0; j < 4; ++j) {
                    float v = acc[m][n][j] + bsv;
                    if (STATS) { cs[n] += v; cq[n] += v * v; }
                    if (POOL) {
                        pmx[m >> 1][n] = fmaxf(pmx[m >> 1][n], v);
                        pmn[m >> 1][n] = fminf(pmn[m >> 1][n], v);
                    }
                    if (EPI == 1) v = fmaxf(v, 0.f);
                    smem[(rbase2 + j) * 136 + col] = f2bf(v);
                }
            }
        }
        if (STATS) {
#pragma unroll
            for (int n = 0; n < 4; ++n) {
                cs[n] += __shfl_xor(cs[n], 16); cs[n] += __shfl_xor(cs[n], 32);
                cq[n] += __shfl_xor(cq[n], 16); cq[n] += __shfl_xor(cq[n], 32);
            }
            if (lane < 16) {
#pragma unroll
                for (int n = 0; n < 4; ++n) {
                    int col = n0 + wc * 64 + n * 16 + lane;
                    atomicAdd(&gsum[col], cs[n]);
                    atomicAdd(&gsq[col],  cq[n]);
                }
            }
        }
        if (POOL) {
#pragma unroll
            for (int gi = 0; gi < 2; ++gi)
#pragma unroll
                for (int n = 0; n < 4; ++n) {
                    pmx[gi][n] = fmaxf(pmx[gi][n], __shfl_xor(pmx[gi][n], 16));
                    pmx[gi][n] = fmaxf(pmx[gi][n], __shfl_xor(pmx[gi][n], 32));
                    pmn[gi][n] = fminf(pmn[gi][n], __shfl_xor(pmn[gi][n], 16));
                    pmn[gi][n] = fminf(pmn[gi][n], __shfl_xor(pmn[gi][n], 32));
                }
            if (lane < 16) {
                int gb = (m0 >> 5) + wr * 2;
#pragma unroll
                for (int gi = 0; gi < 2; ++gi)
#pragma unroll
                    for (int n = 0; n < 4; ++n) {
                        int col = n0 + wc * 64 + n * 16 + lane;
                        gmax[(size_t)(gb + gi) * HID2 + col] = pmx[gi][n];
                        gmin[(size_t)(gb + gi) * HID2 + col] = pmn[gi][n];
                    }
            }
        }
        __syncthreads();
#pragma unroll
        for (int it = 0; it < 8; ++it) {
            int r = it * 16 + (tid >> 4);
            int ch = tid & 15;
            int4 v = *(const int4*)&smem[r * 136 + ch * 8];
            *(int4*)((unsigned short*)Cv + (size_t)(m0 + r) * N + n0 + ch * 8) = v;
        }
    } else {
        float ls = 0.f, lq = 0.f;
#pragma unroll
        for (int m = 0; m < 4; ++m) {
            int row = m0 + wr * 64 + m * 16 + ((lane >> 4) << 2);
#pragma unroll
            for (int n = 0; n < 4; ++n) {
                int col = n0 + wc * 64 + n * 16 + (lane & 15);
                float bsv = bias[col];
#pragma unroll
                for (int j = 0; j < 4; ++j) {
                    float v = acc[m][n][j] + bsv;
                    if (EPI == 1) v = fmaxf(v, 0.f);
                    if (GSTATS) { ls += v; lq += v * v; }
                    ((float*)Cv)[(size_t)(row + j) * N + col] = v;
                }
            }
        }
        if (GSTATS) {
            for (int o = 32; o > 0; o >>= 1) {
                ls += __shfl_down(ls, o);
                lq += __shfl_down(lq, o);
            }
            if (lane == 0) {
                atomicAdd(gacc,     (double)ls);
                atomicAdd(gacc + 1, (double)lq);
            }
        }
    }
}

// ---------------- streaming LN1 stats of relu(bn(h2)); bn2 coeffs computed inline ----------------
__global__ __launch_bounds__(256) void lnstats_h2(const unsigned short* __restrict__ H,
                                                  const float* __restrict__ gsum,
                                                  const float* __restrict__ gsq,
                                                  const float* __restrict__ bw,
                                                  const float* __restrict__ bb,
                                                  float invN,
                                                  double* __restrict__ lnacc) {
    int half = threadIdx.x >> 7;              // 0..1
    int c0 = (threadIdx.x & 127) * 8;
    float sc[8], sh[8];
#pragma unroll
    for (int q = 0; q < 8; ++q) {
        int ch = c0 + q;
        float mu = gsum[ch] * invN;
        float var = gsq[ch] * invN - mu * mu;
        float s = rsqrtf(var + 1e-5f) * bw[ch];
        sc[q] = s;
        sh[q] = bb[ch] - mu * s;
    }
    float lsum = 0.f, lsq = 0.f;
    for (int r = blockIdx.x * 2 + half; r < NNODES; r += gridDim.x * 2) {
        int4 u = *(const int4*)(H + (size_t)r * HID2 + c0);
        const unsigned short* up = (const unsigned short*)&u;
#pragma unroll
        for (int q = 0; q < 8; ++q) {
            float v = fmaxf(bf2f(up[q]) * sc[q] + sh[q], 0.f);
            lsum += v; lsq += v * v;
        }
    }
    for (int o = 32; o > 0; o >>= 1) {
        lsum += __shfl_down(lsum, o);
        lsq  += __shfl_down(lsq, o);
    }
    __shared__ float w1[4], w2[4];
    int wid = threadIdx.x >> 6, lane = threadIdx.x & 63;
    if (lane == 0) { w1[wid] = lsum; w2[wid] = lsq; }
    __syncthreads();
    if (threadIdx.x == 0) {
        atomicAdd(lnacc,     (double)(w1[0] + w1[1] + w1[2] + w1[3]));
        atomicAdd(lnacc + 1, (double)(w2[0] + w2[1] + w2[2] + w2[3]));
    }
}

// ---------------- pool finalize: compose bn+relu+ln over raw max/min; all coeffs inline ----------------
__global__ __launch_bounds__(256) void pool_fin(const float* __restrict__ gmax,
                                                const float* __restrict__ gmin,
                                                const float* __restrict__ bsum,
                                                const float* __restrict__ bsq,
                                                const float* __restrict__ bw,
                                                const float* __restrict__ bb,
                                                const double* __restrict__ lnacc,
                                                const float* __restrict__ lw,
                                                const float* __restrict__ lb,
                                                float invN, double invCnt,
                                                unsigned short* __restrict__ P) {
    int i = blockIdx.x * 256 + threadIdx.x;            // over NGRAPH*HID2/4
    int c0 = (i * 4) & (HID2 - 1);
    double dmu = lnacc[0] * invCnt;
    double dvar = lnacc[1] * invCnt - dmu * dmu;
    if (dvar < 0.0) dvar = 0.0;
    float smu = (float)dmu;
    float sinv = 1.0f / (sqrtf((float)dvar) + 1e-5f);
    float4 mx = ((const float4*)gmax)[i];
    float4 mn = ((const float4*)gmin)[i];
    float r[4];
    const float* mxp = (const float*)&mx;
    const float* mnp = (const float*)&mn;
#pragma unroll
    for (int q = 0; q < 4; ++q) {
        int ch = c0 + q;
        float bmu = bsum[ch] * invN;
        float bvar = bsq[ch] * invN - bmu * bmu;
        float s = rsqrtf(bvar + 1e-5f) * bw[ch];
        float t = bb[ch] - bmu * s;
        float A = sinv * lw[ch];
        float C = lb[ch] - smu * A;
        float vs = ((s >= 0.f) == (A >= 0.f)) ? mxp[q] : mnp[q];
        r[q] = A * fmaxf(s * vs + t, 0.f) + C;
    }
    ushort4 o;
    o.x = f2bf(r[0]); o.y = f2bf(r[1]); o.z = f2bf(r[2]); o.w = f2bf(r[3]);
    ((ushort4*)P)[i] = o;
}

// ---------------- fused LN2 (inline coeffs) + final GEMM [1024,512]@[512,20] + log_softmax ----------------
__global__ __launch_bounds__(64) void gemm4_lsm(const float* __restrict__ Z,
                                                const double* __restrict__ acc2,
                                                const float* __restrict__ lw,
                                                const float* __restrict__ lb,
                                                const float* __restrict__ W,
                                                const float* __restrict__ bias,
                                                double invCnt,
                                                float* __restrict__ out) {
    __shared__ float zs[HID1];
    __shared__ float logits[NCLS];
    __shared__ float smaxs, slse;
    int m = blockIdx.x;
    double dmu = acc2[0] * invCnt;
    double dvar = acc2[1] * invCnt - dmu * dmu;
    if (dvar < 0.0) dvar = 0.0;
    float smu = (float)dmu;
    float sinv = 1.0f / (sqrtf((float)dvar) + 1e-5f);
    for (int k = threadIdx.x; k < HID1; k += 64) {
        float A = sinv * lw[k];
        zs[k] = Z[(size_t)m * HID1 + k] * A + (lb[k] - smu * A);
    }
    __syncthreads();
    if (threadIdx.x < NCLS) {
        float acc = bias[threadIdx.x];
        for (int k = 0; k < HID1; ++k)
            acc += zs[k] * W[k * NCLS + threadIdx.x];
        logits[threadIdx.x] = acc;
    }
    __syncthreads();
    if (threadIdx.x == 0) {
        float mx = -1e30f;
        for (int j = 0; j < NCLS; ++j) mx = fmaxf(mx, logits[j]);
        float s = 0.f;
        for (int j = 0; j < NCLS; ++j) s += expf(logits[j] - mx);
        smaxs = mx; slse = logf(s);
    }
    __syncthreads();
    if (threadIdx.x < NCLS)
        out[(size_t)m * NCLS + threadIdx.x] = logits[threadIdx.x] - smaxs - slse;
}

// ======================== launch ========================
extern "C" void kernel_launch(void* const* d_in, const int* in_sizes, int n_in,
                              void* d_out, int out_size, void* d_ws, size_t ws_size,
                              hipStream_t stream) {
    const float* x       = (const float*)d_in[0];
    const int*   ei      = (const int*)d_in[1];
    const int*   src     = ei;
    const int*   dst     = ei + NEDGES;
    const float* conv1_w = (const float*)d_in[3];
    const float* conv1_b = (const float*)d_in[4];
    const float* bn1_w   = (const float*)d_in[5];
    const float* bn1_b   = (const float*)d_in[6];
    const float* conv2_w = (const float*)d_in[7];
    const float* conv2_b = (const float*)d_in[8];
    const float* bn2_w   = (const float*)d_in[9];
    const float* bn2_b   = (const float*)d_in[10];
    const float* ln1_w   = (const float*)d_in[11];
    const float* ln1_b   = (const float*)d_in[12];
    const float* lin1_w  = (const float*)d_in[13];
    const float* lin1_b  = (const float*)d_in[14];
    const float* ln2_w   = (const float*)d_in[15];
    const float* ln2_b   = (const float*)d_in[16];
    const float* lin2_w  = (const float*)d_in[17];
    const float* lin2_b  = (const float*)d_in[18];
    float* out = (float*)d_out;

    // ---- workspace layout (peak 128 MB) ----
    char* ws = (char*)d_ws;
    const size_t KB = 1024, MB = 1048576;
    float*          dis     = (float*)(ws + 0);            // 128K
    float*          sF      = (float*)(ws + 128 * KB);     // 40K stats
    unsigned short* w1t     = (unsigned short*)(ws + 256 * KB);   // [512][128]  128K
    unsigned short* w2t     = (unsigned short*)(ws + 512 * KB);   // [1024][512] 1M
    unsigned short* w3t     = (unsigned short*)(ws + 1536 * KB);  // [512][1024] 1M
    int*            cnt     = (int*)(ws + 2560 * KB);      // 128K
    int*            offs    = (int*)(ws + 2688 * KB);      // 128K+4 (192K reserved)
    int*            cursor  = (int*)(ws + 2880 * KB);      // 128K
    int2*           csr_e   = (int2*)(ws + 3 * MB);        // 2M {src, w}
    unsigned short* pool    = (unsigned short*)(ws + 5 * MB);   // [1024][1024] bf16 2M
    float*          z       = (float*)(ws + 7 * MB);       // [1024][512] f32 2M
    unsigned short* agg1    = (unsigned short*)(ws + 16 * MB);  // [N,128] bf16 8M   (16-24)
    unsigned short* h1      = (unsigned short*)(ws + 24 * MB);  // [N,512] bf16 32M  (24-56)
    unsigned short* h2      = (unsigned short*)(ws + 16 * MB);  // [N,1024] bf16 64M (16-80)
    float*          gmax    = (float*)(ws + 80 * MB);      // [G,1024] f32 4M (80-84)
    float*          gmin    = (float*)(ws + 84 * MB);      // [G,1024] f32 4M (84-88)
    unsigned short* agg2    = (unsigned short*)(ws + 88 * MB);  // [N,512] bf16 32M  (88-120)
    unsigned short* xb      = (unsigned short*)(ws + 120 * MB); // [N,128] bf16 8M  (120-128)

    float* bn1_sum = sF + 0,      *bn1_sq    = sF + 512;
    float* bn2_sum = sF + 2048,   *bn2_sq    = sF + 3072;
    double* lnacc = (double*)(sF + 9216);   // [0,1]=ln1  [2,3]=ln2

    const float invN = 1.0f / (float)NNODES;

    // ---- fused prologue: zero ∪ f2b ∪ wtrans×3 ----
    prep<<<2488, 256, 0, stream>>>(x, xb, conv1_w, w1t, conv2_w, w2t, lin1_w, w3t, sF, cnt);

    // ---- CSR build (by dst) + dis ----
    csr_count<<<(NEDGES + 255) / 256, 256, 0, stream>>>(dst, cnt);
    csr_scan<<<1, 1024, 0, stream>>>(cnt, offs, cursor, dis);
    csr_fill<<<(NEDGES + 255) / 256, 256, 0, stream>>>(src, dst, dis, cursor, csr_e);

    // ---- conv1: agg1 = A @ xb ; h1 = agg1 @ W1 + b1 (+ bn1 col stats) ----
    gcn_gather<FIN, 0><<<NNODES / 4, 256, 0, stream>>>(xb, offs, csr_e, dis,
                                                       nullptr, nullptr, nullptr, nullptr, 0.f, agg1);
    gemm_mfma<0, 1, 1, 0, 0><<<dim3(HID1 / 128, NNODES / 128), 256, 0, stream>>>(
        agg1, w1t, conv1_b, h1, bn1_sum, bn1_sq, nullptr, nullptr, nullptr, NNODES, HID1, FIN);

    // ---- conv2: gather applies bn1+relu (coeffs inline from raw sums) ----
    gcn_gather<HID1, 1><<<NNODES / 4, 256, 0, stream>>>(h1, offs, csr_e, dis,
                                                        bn1_sum, bn1_sq, bn1_w, bn1_b, invN, agg2);
    gemm_mfma<0, 1, 1, 1, 0><<<dim3(HID2 / 128, NNODES / 128), 256, 0, stream>>>(
        agg2, w2t, conv2_b, h2, bn2_sum, bn2_sq, gmax, gmin, nullptr, NNODES, HID2, HID1);

    // ---- streaming LN1 stats over relu(bn2(h2)) (bn2 coeffs inline) ----
    lnstats_h2<<<1024, 256, 0, stream>>>(h2, bn2_sum, bn2_sq, bn2_w, bn2_b, invN, lnacc);

    // ---- pool finalize (bn2+relu+ln1 composed over raw max/min; all coeffs inline) ----
    pool_fin<<<NGRAPH * HID2 / 4 / 256, 256, 0, stream>>>(
        gmax, gmin, bn2_sum, bn2_sq, bn2_w, bn2_b, lnacc, ln1_w, ln1_b,
        invN, 1.0 / ((double)NNODES * HID2), pool);

    // ---- lin1 + relu (MFMA, f32 out, fused LN2 global stats) ----
    gemm_mfma<1, 0, 0, 0, 1><<<dim3(HID1 / 128, NGRAPH / 128), 256, 0, stream>>>(
        pool, w3t, lin1_b, z, nullptr, nullptr, nullptr, nullptr, lnacc + 2, NGRAPH, HID1, HID2);

    // ---- LN2 (inline) + lin2 + log_softmax ----
    gemm4_lsm<<<NGRAPH, 64, 0, stream>>>(z, lnacc + 2, ln2_w, ln2_b, lin2_w, lin2_b,
                                         1.0 / ((double)NGRAPH * HID1), out);
}

// Round 12
// 256.937 us; speedup vs baseline: 1.8225x; 1.0397x over previous
//
#include <hip/hip_runtime.h>
#include <hip/hip_bf16.h>
#include <hip/hip_fp16.h>

#define NNODES 32768
#define NEDGES 262144
#define FIN    128
#define HID1   512
#define HID2   1024
#define NGRAPH 1024
#define NCLS   20

typedef __attribute__((ext_vector_type(8))) short bf16x8;
typedef __attribute__((ext_vector_type(4))) float f32x4;

// ---- bf16 bit helpers (RNE) ----
__device__ inline float bf2f(unsigned short u) {
    union { unsigned int i; float f; } v; v.i = ((unsigned int)u) << 16; return v.f;
}
__device__ inline unsigned short f2bf(float f) {
    union { unsigned int i; float f; } v; v.f = f;
    unsigned int r = v.i + 0x7FFF + ((v.i >> 16) & 1);
    return (unsigned short)(r >> 16);
}

// ---- 8-bit e5m2 via half (RNE to top byte). Used ONLY for h2, which feeds
// aggregate LN statistics — per-element quantization error averages out. ----
__device__ inline unsigned char f2e5(float f) {
    unsigned short h = __half_as_ushort(__float2half(f));
    unsigned short r = h + 0x7F + ((h >> 8) & 1);
    return (unsigned char)(r >> 8);
}
__device__ inline float e52f(unsigned char b) {
    return __half2float(__ushort_as_half((unsigned short)(b << 8)));
}

// ---- async global -> LDS, 16B per lane ----
typedef unsigned int u32g __attribute__((address_space(1)));
typedef unsigned int u32l __attribute__((address_space(3)));
__device__ inline void load16_lds(const void* g, void* l) {
    __builtin_amdgcn_global_load_lds((const u32g*)g, (u32l*)l, 16, 0, 0);
}

// ================= fused prologue: zero ∪ f2b ∪ wtrans×3 (blockIdx-partitioned) =================
__device__ inline void wtrans_body(const float* __restrict__ W, unsigned short* __restrict__ Wt,
                                   int K, int N, int bx, int by, unsigned short (*tile)[72]) {
    int kb = by * 64, nb = bx * 64;
    {
        int k = threadIdx.x >> 2;
        int n0 = (threadIdx.x & 3) * 16;
#pragma unroll
        for (int q = 0; q < 4; ++q) {
            float4 v = *(const float4*)(W + (size_t)(kb + k) * N + nb + n0 + q * 4);
            tile[k][n0 + q * 4 + 0] = f2bf(v.x);
            tile[k][n0 + q * 4 + 1] = f2bf(v.y);
            tile[k][n0 + q * 4 + 2] = f2bf(v.z);
            tile[k][n0 + q * 4 + 3] = f2bf(v.w);
        }
    }
    __syncthreads();
    {
        int n = threadIdx.x >> 2;
        int k0 = (threadIdx.x & 3) * 16;
#pragma unroll
        for (int q = 0; q < 4; ++q) {
            ushort4 u;
            u.x = tile[k0 + q * 4 + 0][n];
            u.y = tile[k0 + q * 4 + 1][n];
            u.z = tile[k0 + q * 4 + 2][n];
            u.w = tile[k0 + q * 4 + 3][n];
            *(ushort4*)(Wt + (size_t)(nb + n) * K + kb + k0 + q * 4) = u;
        }
    }
}

// block ranges: [0,168) zero | [168,2216) f2b | [2216,2232) w1 | [2232,2360) w2 | [2360,2488) w3
__global__ __launch_bounds__(256) void prep(const float* __restrict__ x, unsigned short* __restrict__ xb,
                                            const float* __restrict__ W1, unsigned short* __restrict__ w1t,
                                            const float* __restrict__ W2, unsigned short* __restrict__ w2t,
                                            const float* __restrict__ W3, unsigned short* __restrict__ w3t,
                                            float* __restrict__ sF, int* __restrict__ cnt) {
    __shared__ unsigned short tile[64][72];
    int b = blockIdx.x;
    if (b < 168) {
        int t = b * 256 + threadIdx.x;
        if (t < 10240) sF[t] = 0.f;
        if (t < NNODES) cnt[t] = 0;
    } else if (b < 2216) {
        int i = (b - 168) * 256 + threadIdx.x;   // < 524288
        float4 a = ((const float4*)x)[i * 2];
        float4 c = ((const float4*)x)[i * 2 + 1];
        ushort4 u0, u1;
        u0.x = f2bf(a.x); u0.y = f2bf(a.y); u0.z = f2bf(a.z); u0.w = f2bf(a.w);
        u1.x = f2bf(c.x); u1.y = f2bf(c.y); u1.z = f2bf(c.z); u1.w = f2bf(c.w);
        ((ushort4*)xb)[i * 2] = u0;
        ((ushort4*)xb)[i * 2 + 1] = u1;
    } else if (b < 2232) {
        int q = b - 2216;                         // 16 blocks: bx 8, by 2
        wtrans_body(W1, w1t, FIN, HID1, q & 7, q >> 3, tile);
    } else if (b < 2360) {
        int q = b - 2232;                         // 128 blocks: bx 16, by 8
        wtrans_body(W2, w2t, HID1, HID2, q & 15, q >> 4, tile);
    } else {
        int q = b - 2360;                         // 128 blocks: bx 8, by 16
        wtrans_body(W3, w3t, HID2, HID1, q & 7, q >> 3, tile);
    }
}

// ================= CSR build (by dst), interleaved {src, w} =================
__global__ __launch_bounds__(256) void csr_count(const int* __restrict__ dst, int* __restrict__ cnt) {
    int e = blockIdx.x * 256 + threadIdx.x;
    if (e < NEDGES) atomicAdd(&cnt[dst[e]], 1);
}

__global__ __launch_bounds__(1024) void csr_scan(const int* __restrict__ cnt,
                                                 int* __restrict__ offs,
                                                 int* __restrict__ cursor,
                                                 float* __restrict__ dis) {
    __shared__ int part[1024];
    int t = threadIdx.x;
    int base = t * 32;
    int c[32];
#pragma unroll
    for (int j = 0; j < 8; ++j) {
        int4 u = *(const int4*)(cnt + base + j * 4);
        c[j * 4 + 0] = u.x; c[j * 4 + 1] = u.y; c[j * 4 + 2] = u.z; c[j * 4 + 3] = u.w;
    }
    int s = 0;
#pragma unroll
    for (int i = 0; i < 32; ++i) s += c[i];
    part[t] = s;
    __syncthreads();
    for (int off = 1; off < 1024; off <<= 1) {
        int v = (t >= off) ? part[t - off] : 0;
        __syncthreads();
        part[t] += v;
        __syncthreads();
    }
    int run = (t == 0) ? 0 : part[t - 1];
    int ov[32]; float dv[32];
#pragma unroll
    for (int i = 0; i < 32; ++i) {
        ov[i] = run;
        dv[i] = rsqrtf((float)(c[i] + 1));
        run += c[i];
    }
#pragma unroll
    for (int j = 0; j < 8; ++j) {
        int4 o4 = make_int4(ov[j * 4], ov[j * 4 + 1], ov[j * 4 + 2], ov[j * 4 + 3]);
        *(int4*)(offs + base + j * 4) = o4;
        *(int4*)(cursor + base + j * 4) = o4;
        *(float4*)(dis + base + j * 4) = make_float4(dv[j * 4], dv[j * 4 + 1], dv[j * 4 + 2], dv[j * 4 + 3]);
    }
    if (t == 1023) offs[NNODES] = run;
}

__global__ __launch_bounds__(256) void csr_fill(const int* __restrict__ src,
                                                const int* __restrict__ dst,
                                                const float* __restrict__ dis,
                                                int* __restrict__ cursor,
                                                int2* __restrict__ csr_e) {
    int e = blockIdx.x * 256 + threadIdx.x;
    if (e >= NEDGES) return;
    int s = src[e], d = dst[e];
    int pos = atomicAdd(&cursor[d], 1);
    int2 v; v.x = s; v.y = __float_as_int(dis[s] * dis[d]);
    csr_e[pos] = v;
}

// ================= gather aggregation (bf16 in, bf16 out), one wave per node =================
template<int F, int BNF>
__global__ __launch_bounds__(256) void gcn_gather(const unsigned short* __restrict__ X,
                                                  const int* __restrict__ offs,
                                                  const int2* __restrict__ csr_e,
                                                  const float* __restrict__ dis,
                                                  const float* __restrict__ gsum,
                                                  const float* __restrict__ gsq,
                                                  const float* __restrict__ bw,
                                                  const float* __restrict__ bb,
                                                  float invN,
                                                  unsigned short* __restrict__ out) {
    constexpr int CPL = F / 64;          // 2 (F=128) or 8 (F=512)
    int wave = threadIdx.x >> 6, lane = threadIdx.x & 63;
    int node = blockIdx.x * 4 + wave;
    int c0 = lane * CPL;
    const unsigned short* Xc = X + c0;
    float acc[CPL];
#pragma unroll
    for (int q = 0; q < CPL; ++q) acc[q] = 0.f;
    float sc[CPL], sh[CPL];
    if (BNF) {
#pragma unroll
        for (int q = 0; q < CPL; ++q) {
            int ch = c0 + q;
            float mu = gsum[ch] * invN;
            float var = gsq[ch] * invN - mu * mu;
            float s = rsqrtf(var + 1e-5f) * bw[ch];
            sc[q] = s;
            sh[q] = bb[ch] - mu * s;
        }
    }

    auto accum = [&](int s, float w) {
        if (CPL == 8) {
            int4 u = *(const int4*)(Xc + (size_t)s * F);
            const unsigned short* up = (const unsigned short*)&u;
#pragma unroll
            for (int q = 0; q < 8; ++q) {
                float v = bf2f(up[q]);
                if (BNF) v = fmaxf(v * sc[q] + sh[q], 0.f);
                acc[q] += w * v;
            }
        } else {
            ushort2 u = *(const ushort2*)(Xc + (size_t)s * F);
            float v0 = bf2f(u.x), v1 = bf2f(u.y);
            if (BNF) {
                v0 = fmaxf(v0 * sc[0] + sh[0], 0.f);
                v1 = fmaxf(v1 * sc[1] + sh[1], 0.f);
            }
            acc[0] += w * v0; acc[1] += w * v1;
        }
    };

    float sw = dis[node]; sw *= sw;
    accum(node, sw);                       // self-loop term

    int e0 = offs[node], e1 = offs[node + 1];
    int e = e0;
    for (; e + 8 <= e1; e += 8) {
        int2 ed[8];
#pragma unroll
        for (int j = 0; j < 8; ++j) ed[j] = csr_e[e + j];
#pragma unroll
        for (int j = 0; j < 8; ++j) accum(ed[j].x, __int_as_float(ed[j].y));
    }
    for (; e + 4 <= e1; e += 4) {
        int2 ed[4];
#pragma unroll
        for (int j = 0; j < 4; ++j) ed[j] = csr_e[e + j];
#pragma unroll
        for (int j = 0; j < 4; ++j) accum(ed[j].x, __int_as_float(ed[j].y));
    }
    for (; e < e1; ++e) {
        int2 ed = csr_e[e];
        accum(ed.x, __int_as_float(ed.y));
    }

    unsigned short* o = out + (size_t)node * F + c0;
    if (CPL == 2) {
        ushort2 u; u.x = f2bf(acc[0]); u.y = f2bf(acc[1]);
        *(ushort2*)o = u;
    } else {
        ushort4 u0, u1;
        u0.x = f2bf(acc[0]); u0.y = f2bf(acc[1]); u0.z = f2bf(acc[2]); u0.w = f2bf(acc[3]);
        u1.x = f2bf(acc[4]); u1.y = f2bf(acc[5]); u1.z = f2bf(acc[6]); u1.w = f2bf(acc[7]);
        *(ushort4*)o = u0;
        *(ushort4*)(o + 4) = u1;
    }
}

// ================= bf16 MFMA GEMM: C[M][N] = A[M][K] @ B (Bt[N][K]) =================
// 128x128 tile, BK=64, 4 waves. global_load_lds staging; LDS XOR-swizzle via pre-swizzled source.
// CBF16=1: LDS-staged coalesced store (CF8=1: 8-bit e5m2 output, else bf16).
// STATS=1: per-column sum/sumsq atomics. POOL=1: per-graph raw max/min. GSTATS=1 (f32): global sum/sq.
template<int EPI, int CBF16, int STATS, int POOL, int GSTATS, int CF8>
__global__ __launch_bounds__(256, 2) void gemm_mfma(const unsigned short* __restrict__ A,
                                                    const unsigned short* __restrict__ Bt,
                                                    const float* __restrict__ bias,
                                                    void* __restrict__ Cv,
                                                    float* __restrict__ gsum,
                                                    float* __restrict__ gsq,
                                                    float* __restrict__ gmax,
                                                    float* __restrict__ gmin,
                                                    double* __restrict__ gacc,
                                                    int M, int N, int K) {
    constexpr int BM = 128, BN = 128, BK = 64;
    __shared__ unsigned short smem[128 * 136];
    unsigned short* As = smem;
    unsigned short* Bs = smem + BM * BK;

    const int tid = threadIdx.x;
    const int lane = tid & 63;
    const int wave = tid >> 6;
    const int wr = wave >> 1, wc = wave & 1;

    const int nwg = gridDim.x * gridDim.y;
    const int wg = blockIdx.y * gridDim.x + blockIdx.x;
    const int cpx = nwg >> 3;
    const int swz = (wg & 7) * cpx + (wg >> 3);
    const int m0 = (swz / gridDim.x) * BM, n0 = (swz % gridDim.x) * BN;

    const int sub = ((tid & 7) * 16) ^ (((tid >> 3) & 7) << 4);
    const int rbase = tid >> 3;
    const char* Ab = (const char*)A + sub;
    const char* Bb = (const char*)Bt + sub;

    f32x4 acc[4][4] = {};

    for (int k0 = 0; k0 < K; k0 += BK) {
        __syncthreads();
#pragma unroll
        for (int i = 0; i < 4; ++i) {
            int r = i * 32 + rbase;
            load16_lds(Ab + ((size_t)(m0 + r) * K + k0) * 2, (char*)As + i * 4096 + tid * 16);
            load16_lds(Bb + ((size_t)(n0 + r) * K + k0) * 2, (char*)Bs + i * 4096 + tid * 16);
        }
        __syncthreads();
#pragma unroll
        for (int ks = 0; ks < 2; ++ks) {
            bf16x8 af[4], bfr[4];
#pragma unroll
            for (int m = 0; m < 4; ++m) {
                int row = wr * 64 + m * 16 + (lane & 15);
                int s = (ks * 64 + ((lane >> 4) * 16)) ^ ((row & 7) << 4);
                af[m] = *(const bf16x8*)((const char*)As + row * 128 + s);
            }
#pragma unroll
            for (int n = 0; n < 4; ++n) {
                int row = wc * 64 + n * 16 + (lane & 15);
                int s = (ks * 64 + ((lane >> 4) * 16)) ^ ((row & 7) << 4);
                bfr[n] = *(const bf16x8*)((const char*)Bs + row * 128 + s);
            }
#pragma unroll
            for (int m = 0; m < 4; ++m)
#pragma unroll
                for (int n = 0; n < 4; ++n)
                    acc[m][n] = __builtin_amdgcn_mfma_f32_16x16x32_bf16(af[m], bfr[n], acc[m][n], 0, 0, 0);
        }
    }

    // ---- epilogue ----
    if (CBF16) {
        __syncthreads();
        unsigned char* ctile = (unsigned char*)smem;   // CF8 tile: [128][144] bytes
        float cs[4], cq[4];
        float pmx[2][4], pmn[2][4];
#pragma unroll
        for (int n = 0; n < 4; ++n) {
            cs[n] = 0.f; cq[n] = 0.f;
            if (POOL) {
                pmx[0][n] = -1e30f; pmx[1][n] = -1e30f;
                pmn[0][n] = 1e30f;  pmn[1][n] = 1e30f;
            }
        }
#pragma unroll
        for (int n = 0; n < 4; ++n) {
            int col = wc * 64 + n * 16 + (lane & 15);
            float bsv = bias[n0 + col];
#pragma unroll
            for (int m = 0; m < 4; ++m) {
                int rbase2 = wr * 64 + m * 16 + ((lane >> 4) << 2);
#pragma unroll
                for (int j = 0; j < 4; ++j) {
                    float v = acc[m][n][j] + bsv;
                    if (STATS) { cs[n] += v; cq[n] += v * v; }
                    if (POOL) {
                        pmx[m >> 1][n] = fmaxf(pmx[m >> 1][n], v);
                        pmn[m >> 1][n] = fminf(pmn[m >> 1][n], v);
                    }
                    if (EPI == 1) v = fmaxf(v, 0.f);
                    if (CF8) ctile[(rbase2 + j) * 144 + col] = f2e5(v);
                    else     smem[(rbase2 + j) * 136 + col] = f2bf(v);
                }
            }
        }
        if (STATS) {
#pragma unroll
            for (int n = 0; n < 4; ++n) {
                cs[n] += __shfl_xor(cs[n], 16); cs[n] += __shfl_xor(cs[n], 32);
                cq[n] += __shfl_xor(cq[n], 16); cq[n] += __shfl_xor(cq[n], 32);
            }
            if (lane < 16) {
#pragma unroll
                for (int n = 0; n < 4; ++n) {
                    int col = n0 + wc * 64 + n * 16 + lane;
                    atomicAdd(&gsum[col], cs[n]);
                    atomicAdd(&gsq[col],  cq[n]);
                }
            }
        }
        if (POOL) {
#pragma unroll
            for (int gi = 0; gi < 2; ++gi)
#pragma unroll
                for (int n = 0; n < 4; ++n) {
                    pmx[gi][n] = fmaxf(pmx[gi][n], __shfl_xor(pmx[gi][n], 16));
                    pmx[gi][n] = fmaxf(pmx[gi][n], __shfl_xor(pmx[gi][n], 32));
                    pmn[gi][n] = fminf(pmn[gi][n], __shfl_xor(pmn[gi][n], 16));
                    pmn[gi][n] = fminf(pmn[gi][n], __shfl_xor(pmn[gi][n], 32));
                }
            if (lane < 16) {
                int gb = (m0 >> 5) + wr * 2;
#pragma unroll
                for (int gi = 0; gi < 2; ++gi)
#pragma unroll
                    for (int n = 0; n < 4; ++n) {
                        int col = n0 + wc * 64 + n * 16 + lane;
                        gmax[(size_t)(gb + gi) * HID2 + col] = pmx[gi][n];
                        gmin[(size_t)(gb + gi) * HID2 + col] = pmn[gi][n];
                    }
            }
        }
        __syncthreads();
        if (CF8) {
            // 1024 chunks of 16B (128 rows x 8 chunks), 4 per thread
#pragma unroll
            for (int it = 0; it < 4; ++it) {
                int l = it * 256 + tid;
                int r = l >> 3, ch = l & 7;
                int4 v = *(const int4*)(ctile + r * 144 + ch * 16);
                *(int4*)((unsigned char*)Cv + (size_t)(m0 + r) * N + n0 + ch * 16) = v;
            }
        } else {
#pragma unroll
            for (int it = 0; it < 8; ++it) {
                int r = it * 16 + (tid >> 4);
                int ch = tid & 15;
                int4 v = *(const int4*)&smem[r * 136 + ch * 8];
                *(int4*)((unsigned short*)Cv + (size_t)(m0 + r) * N + n0 + ch * 8) = v;
            }
        }
    } else {
        float ls = 0.f, lq = 0.f;
#pragma unroll
        for (int m = 0; m < 4; ++m) {
            int row = m0 + wr * 64 + m * 16 + ((lane >> 4) << 2);
#pragma unroll
            for (int n = 0; n < 4; ++n) {
                int col = n0 + wc * 64 + n * 16 + (lane & 15);
                float bsv = bias[col];
#pragma unroll
                for (int j = 0; j < 4; ++j) {
                    float v = acc[m][n][j] + bsv;
                    if (EPI == 1) v = fmaxf(v, 0.f);
                    if (GSTATS) { ls += v; lq += v * v; }
                    ((float*)Cv)[(size_t)(row + j) * N + col] = v;
                }
            }
        }
        if (GSTATS) {
            for (int o = 32; o > 0; o >>= 1) {
                ls += __shfl_down(ls, o);
                lq += __shfl_down(lq, o);
            }
            if (lane == 0) {
                atomicAdd(gacc,     (double)ls);
                atomicAdd(gacc + 1, (double)lq);
            }
        }
    }
}

// ---------------- streaming LN1 stats of relu(bn(h2)), h2 is 8-bit e5m2; bn2 coeffs inline ----------------
__global__ __launch_bounds__(256) void lnstats_h2(const unsigned char* __restrict__ H,
                                                  const float* __restrict__ gsum,
                                                  const float* __restrict__ gsq,
                                                  const float* __restrict__ bw,
                                                  const float* __restrict__ bb,
                                                  float invN,
                                                  double* __restrict__ lnacc) {
    int half = threadIdx.x >> 7;              // 0..1
    int c0 = (threadIdx.x & 127) * 8;
    float sc[8], sh[8];
#pragma unroll
    for (int q = 0; q < 8; ++q) {
        int ch = c0 + q;
        float mu = gsum[ch] * invN;
        float var = gsq[ch] * invN - mu * mu;
        float s = rsqrtf(var + 1e-5f) * bw[ch];
        sc[q] = s;
        sh[q] = bb[ch] - mu * s;
    }
    float lsum = 0.f, lsq = 0.f;
    for (int r = blockIdx.x * 2 + half; r < NNODES; r += gridDim.x * 2) {
        uint2 u = *(const uint2*)(H + (size_t)r * HID2 + c0);
        const unsigned char* up = (const unsigned char*)&u;
#pragma unroll
        for (int q = 0; q < 8; ++q) {
            float v = fmaxf(e52f(up[q]) * sc[q] + sh[q], 0.f);
            lsum += v; lsq += v * v;
        }
    }
    for (int o = 32; o > 0; o >>= 1) {
        lsum += __shfl_down(lsum, o);
        lsq  += __shfl_down(lsq, o);
    }
    __shared__ float w1[4], w2[4];
    int wid = threadIdx.x >> 6, lane = threadIdx.x & 63;
    if (lane == 0) { w1[wid] = lsum; w2[wid] = lsq; }
    __syncthreads();
    if (threadIdx.x == 0) {
        atomicAdd(lnacc,     (double)(w1[0] + w1[1] + w1[2] + w1[3]));
        atomicAdd(lnacc + 1, (double)(w2[0] + w2[1] + w2[2] + w2[3]));
    }
}

// ---------------- pool finalize: compose bn+relu+ln over raw max/min; all coeffs inline ----------------
__global__ __launch_bounds__(256) void pool_fin(const float* __restrict__ gmax,
                                                const float* __restrict__ gmin,
                                                const float* __restrict__ bsum,
                                                const float* __restrict__ bsq,
                                                const float* __restrict__ bw,
                                                const float* __restrict__ bb,
                                                const double* __restrict__ lnacc,
                                                const float* __restrict__ lw,
                                                const float* __restrict__ lb,
                                                float invN, double invCnt,
                                                unsigned short* __restrict__ P) {
    int i = blockIdx.x * 256 + threadIdx.x;            // over NGRAPH*HID2/4
    int c0 = (i * 4) & (HID2 - 1);
    double dmu = lnacc[0] * invCnt;
    double dvar = lnacc[1] * invCnt - dmu * dmu;
    if (dvar < 0.0) dvar = 0.0;
    float smu = (float)dmu;
    float sinv = 1.0f / (sqrtf((float)dvar) + 1e-5f);
    float4 mx = ((const float4*)gmax)[i];
    float4 mn = ((const float4*)gmin)[i];
    float r[4];
    const float* mxp = (const float*)&mx;
    const float* mnp = (const float*)&mn;
#pragma unroll
    for (int q = 0; q < 4; ++q) {
        int ch = c0 + q;
        float bmu = bsum[ch] * invN;
        float bvar = bsq[ch] * invN - bmu * bmu;
        float s = rsqrtf(bvar + 1e-5f) * bw[ch];
        float t = bb[ch] - bmu * s;
        float A = sinv * lw[ch];
        float C = lb[ch] - smu * A;
        float vs = ((s >= 0.f) == (A >= 0.f)) ? mxp[q] : mnp[q];
        r[q] = A * fmaxf(s * vs + t, 0.f) + C;
    }
    ushort4 o;
    o.x = f2bf(r[0]); o.y = f2bf(r[1]); o.z = f2bf(r[2]); o.w = f2bf(r[3]);
    ((ushort4*)P)[i] = o;
}

// ---------------- fused LN2 (inline coeffs) + final GEMM [1024,512]@[512,20] + log_softmax ----------------
// 256 threads: 160 compute 20 classes x 8 k-slices, LDS reduce.
__global__ __launch_bounds__(256) void gemm4_lsm(const float* __restrict__ Z,
                                                 const double* __restrict__ acc2,
                                                 const float* __restrict__ lw,
                                                 const float* __restrict__ lb,
                                                 const float* __restrict__ W,
                                                 const float* __restrict__ bias,
                                                 double invCnt,
                                                 float* __restrict__ out) {
    __shared__ float zs[HID1];
    __shared__ float part[8][NCLS];
    __shared__ float logits[NCLS];
    __shared__ float smaxs, slse;
    int m = blockIdx.x;
    double dmu = acc2[0] * invCnt;
    double dvar = acc2[1] * invCnt - dmu * dmu;
    if (dvar < 0.0) dvar = 0.0;
    float smu = (float)dmu;
    float sinv = 1.0f / (sqrtf((float)dvar) + 1e-5f);
    for (int k = threadIdx.x; k < HID1; k += 256) {
        float A = sinv * lw[k];
        zs[k] = Z[(size_t)m * HID1 + k] * A + (lb[k] - smu * A);
    }
    __syncthreads();
    int t = threadIdx.x;
    if (t < 160) {
        int c = t >> 3, s = t & 7;
        float a = 0.f;
        int k0 = s * 64;
#pragma unroll 8
        for (int k = k0; k < k0 + 64; ++k)
            a += zs[k] * W[k * NCLS + c];
        part[s][c] = a;
    }
    __syncthreads();
    if (t < NCLS) {
        float a = bias[t];
#pragma unroll
        for (int s = 0; s < 8; ++s) a += part[s][t];
        logits[t] = a;
    }
    __syncthreads();
    if (t == 0) {
        float mx = -1e30f;
        for (int j = 0; j < NCLS; ++j) mx = fmaxf(mx, logits[j]);
        float s = 0.f;
        for (int j = 0; j < NCLS; ++j) s += expf(logits[j] - mx);
        smaxs = mx; slse = logf(s);
    }
    __syncthreads();
    if (t < NCLS)
        out[(size_t)m * NCLS + t] = logits[t] - smaxs - slse;
}

// ======================== launch ========================
extern "C" void kernel_launch(void* const* d_in, const int* in_sizes, int n_in,
                              void* d_out, int out_size, void* d_ws, size_t ws_size,
                              hipStream_t stream) {
    const float* x       = (const float*)d_in[0];
    const int*   ei      = (const int*)d_in[1];
    const int*   src     = ei;
    const int*   dst     = ei + NEDGES;
    const float* conv1_w = (const float*)d_in[3];
    const float* conv1_b = (const float*)d_in[4];
    const float* bn1_w   = (const float*)d_in[5];
    const float* bn1_b   = (const float*)d_in[6];
    const float* conv2_w = (const float*)d_in[7];
    const float* conv2_b = (const float*)d_in[8];
    const float* bn2_w   = (const float*)d_in[9];
    const float* bn2_b   = (const float*)d_in[10];
    const float* ln1_w   = (const float*)d_in[11];
    const float* ln1_b   = (const float*)d_in[12];
    const float* lin1_w  = (const float*)d_in[13];
    const float* lin1_b  = (const float*)d_in[14];
    const float* ln2_w   = (const float*)d_in[15];
    const float* ln2_b   = (const float*)d_in[16];
    const float* lin2_w  = (const float*)d_in[17];
    const float* lin2_b  = (const float*)d_in[18];
    float* out = (float*)d_out;

    // ---- workspace layout (peak 128 MB) ----
    char* ws = (char*)d_ws;
    const size_t KB = 1024, MB = 1048576;
    float*          dis     = (float*)(ws + 0);            // 128K
    float*          sF      = (float*)(ws + 128 * KB);     // 40K stats
    unsigned short* w1t     = (unsigned short*)(ws + 256 * KB);   // [512][128]  128K
    unsigned short* w2t     = (unsigned short*)(ws + 512 * KB);   // [1024][512] 1M
    unsigned short* w3t     = (unsigned short*)(ws + 1536 * KB);  // [512][1024] 1M
    int*            cnt     = (int*)(ws + 2560 * KB);      // 128K
    int*            offs    = (int*)(ws + 2688 * KB);      // 128K+4 (192K reserved)
    int*            cursor  = (int*)(ws + 2880 * KB);      // 128K
    int2*           csr_e   = (int2*)(ws + 3 * MB);        // 2M {src, w}
    unsigned short* pool    = (unsigned short*)(ws + 5 * MB);   // [1024][1024] bf16 2M
    float*          z       = (float*)(ws + 7 * MB);       // [1024][512] f32 2M
    unsigned short* agg1    = (unsigned short*)(ws + 16 * MB);  // [N,128] bf16 8M   (16-24)
    unsigned short* h1      = (unsigned short*)(ws + 24 * MB);  // [N,512] bf16 32M  (24-56)
    unsigned char*  h2      = (unsigned char*)(ws + 16 * MB);   // [N,1024] e5m2 32M (16-48, overlays dead agg1+h1)
    float*          gmax    = (float*)(ws + 80 * MB);      // [G,1024] f32 4M (80-84)
    float*          gmin    = (float*)(ws + 84 * MB);      // [G,1024] f32 4M (84-88)
    unsigned short* agg2    = (unsigned short*)(ws + 88 * MB);  // [N,512] bf16 32M  (88-120)
    unsigned short* xb      = (unsigned short*)(ws + 120 * MB); // [N,128] bf16 8M  (120-128)

    float* bn1_sum = sF + 0,      *bn1_sq    = sF + 512;
    float* bn2_sum = sF + 2048,   *bn2_sq    = sF + 3072;
    double* lnacc = (double*)(sF + 9216);   // [0,1]=ln1  [2,3]=ln2

    const float invN = 1.0f / (float)NNODES;

    // ---- fused prologue: zero ∪ f2b ∪ wtrans×3 ----
    prep<<<2488, 256, 0, stream>>>(x, xb, conv1_w, w1t, conv2_w, w2t, lin1_w, w3t, sF, cnt);

    // ---- CSR build (by dst) + dis ----
    csr_count<<<(NEDGES + 255) / 256, 256, 0, stream>>>(dst, cnt);
    csr_scan<<<1, 1024, 0, stream>>>(cnt, offs, cursor, dis);
    csr_fill<<<(NEDGES + 255) / 256, 256, 0, stream>>>(src, dst, dis, cursor, csr_e);

    // ---- conv1: agg1 = A @ xb ; h1 = agg1 @ W1 + b1 (+ bn1 col stats), bf16 out ----
    gcn_gather<FIN, 0><<<NNODES / 4, 256, 0, stream>>>(xb, offs, csr_e, dis,
                                                       nullptr, nullptr, nullptr, nullptr, 0.f, agg1);
    gemm_mfma<0, 1, 1, 0, 0, 0><<<dim3(HID1 / 128, NNODES / 128), 256, 0, stream>>>(
        agg1, w1t, conv1_b, h1, bn1_sum, bn1_sq, nullptr, nullptr, nullptr, NNODES, HID1, FIN);

    // ---- conv2: gather applies bn1+relu (coeffs inline); gemm writes h2 as 8-bit + stats + pool ----
    gcn_gather<HID1, 1><<<NNODES / 4, 256, 0, stream>>>(h1, offs, csr_e, dis,
                                                        bn1_sum, bn1_sq, bn1_w, bn1_b, invN, agg2);
    gemm_mfma<0, 1, 1, 1, 0, 1><<<dim3(HID2 / 128, NNODES / 128), 256, 0, stream>>>(
        agg2, w2t, conv2_b, h2, bn2_sum, bn2_sq, gmax, gmin, nullptr, NNODES, HID2, HID1);

    // ---- streaming LN1 stats over relu(bn2(h2)) (bn2 coeffs inline) ----
    lnstats_h2<<<1024, 256, 0, stream>>>(h2, bn2_sum, bn2_sq, bn2_w, bn2_b, invN, lnacc);

    // ---- pool finalize (bn2+relu+ln1 composed over raw max/min; all coeffs inline) ----
    pool_fin<<<NGRAPH * HID2 / 4 / 256, 256, 0, stream>>>(
        gmax, gmin, bn2_sum, bn2_sq, bn2_w, bn2_b, lnacc, ln1_w, ln1_b,
        invN, 1.0 / ((double)NNODES * HID2), pool);

    // ---- lin1 + relu (MFMA, f32 out, fused LN2 global stats) ----
    gemm_mfma<1, 0, 0, 0, 1, 0><<<dim3(HID1 / 128, NGRAPH / 128), 256, 0, stream>>>(
        pool, w3t, lin1_b, z, nullptr, nullptr, nullptr, nullptr, lnacc + 2, NGRAPH, HID1, HID2);

    // ---- LN2 (inline) + lin2 + log_softmax ----
    gemm4_lsm<<<NGRAPH, 256, 0, stream>>>(z, lnacc + 2, ln2_w, ln2_b, lin2_w, lin2_b,
                                          1.0 / ((double)NGRAPH * HID1), out);
}